// Round 15
// baseline (152.879 us; speedup 1.0000x reference)
//
#include <hip/hip_runtime.h>
#include <stdint.h>

#define HH 16
#define DHD 64
#define BB 2
#define NN 2048
#define DD 1024
#define MMOD 4
#define LMAX 256
#define BNROWS (BB*NN)      // 4096
#define QKVN (3*HH*DHD)     // 3072

typedef __attribute__((ext_vector_type(4))) float f32x4;
typedef __attribute__((ext_vector_type(16))) float f32x16;
typedef __attribute__((ext_vector_type(8))) short s16x8;
typedef __attribute__((ext_vector_type(4))) short s16x4;

__device__ __forceinline__ float bf2f(unsigned short b) {
  return __uint_as_float(((unsigned int)b) << 16);
}
__device__ __forceinline__ unsigned short f2bf(float f) {
  unsigned int u = __float_as_uint(f);
  u += 0x7fffu + ((u >> 16) & 1u);
  return (unsigned short)(u >> 16);
}
__device__ __forceinline__ unsigned int cvt_pk_bf16(float a, float b) {
  unsigned int r;
  asm("v_cvt_pk_bf16_f32 %0, %1, %2" : "=v"(r) : "v"(a), "v"(b));
  return r;
}

#define ASYNC_LDS16(g, l) \
  __builtin_amdgcn_global_load_lds((const __attribute__((address_space(1))) void*)(g), \
                                   (__attribute__((address_space(3))) void*)(l), 16, 0, 0)

// ---------------------------------------------------------------------------
// K1: modality splice + norm + gamma, write xn bf16 [4096][1024]
// ---------------------------------------------------------------------------
__global__ __launch_bounds__(256) void k_prep(const float* __restrict__ x,
                                              const float* __restrict__ tokens,
                                              const float* __restrict__ gamma,
                                              const int* __restrict__ mods,
                                              unsigned short* __restrict__ xn) {
  int bs = blockIdx.x;
  int bb = bs / NN, s = bs % NN;
  int t = threadIdx.x;
  int c = t * 4;
  const float4 xv = *(const float4*)(x + (size_t)bs * DD + c);
  float4 acc = {0.f, 0.f, 0.f, 0.f};
  bool any = false;
  #pragma unroll
  for (int m = 0; m < MMOD; ++m) {
    int off = mods[(bb * MMOD + m) * 3 + 1];
    int ln  = mods[(bb * MMOD + m) * 3 + 2];
    if (s >= off && s < off + ln) {
      any = true;
      int rel = s - off;
      if (rel > LMAX - 1) rel = LMAX - 1;
      if (rel < 0) rel = 0;
      const float4 tv = *(const float4*)(tokens + ((size_t)(bb * MMOD + m) * LMAX + rel) * DD + c);
      acc.x += tv.x; acc.y += tv.y; acc.z += tv.z; acc.w += tv.w;
    }
  }
  float4 v = any ? acc : xv;
  float ss = v.x*v.x + v.y*v.y + v.z*v.z + v.w*v.w;
  #pragma unroll
  for (int o = 32; o; o >>= 1) ss += __shfl_xor(ss, o);
  __shared__ float red[4];
  int wv = t >> 6;
  if ((t & 63) == 0) red[wv] = ss;
  __syncthreads();
  float tot = red[0] + red[1] + red[2] + red[3];
  float norm = sqrtf(tot);
  norm = fmaxf(norm, 1e-12f);
  float sc = 32.0f / norm;   // sqrt(1024) = 32
  const float4 g = *(const float4*)(gamma + c);
  unsigned long long pk =
      (unsigned long long)f2bf(v.x * sc * (g.x + 1.f)) |
      ((unsigned long long)f2bf(v.y * sc * (g.y + 1.f)) << 16) |
      ((unsigned long long)f2bf(v.z * sc * (g.z + 1.f)) << 32) |
      ((unsigned long long)f2bf(v.w * sc * (g.w + 1.f)) << 48);
  *(unsigned long long*)(xn + (size_t)bs * DD + c) = pk;
}

// ---------------------------------------------------------------------------
// K2: pos[b][n] = s - cumsum(rot_any). One wave per batch.
// ---------------------------------------------------------------------------
__global__ void k_pos(const int* __restrict__ mods, int* __restrict__ pos) {
  int bb = blockIdx.x;
  int lane = threadIdx.x;       // 64
  int offs[MMOD], ends[MMOD];
  #pragma unroll
  for (int m = 0; m < MMOD; ++m) {
    int off = mods[(bb * MMOD + m) * 3 + 1];
    int ln  = mods[(bb * MMOD + m) * 3 + 2];
    offs[m] = off + 1;
    ends[m] = off + ln;
  }
  int base = lane * (NN / 64);  // 32 per lane
  int lc[NN / 64];
  int tot = 0;
  #pragma unroll
  for (int i = 0; i < NN / 64; ++i) {
    int s = base + i;
    int f = 0;
    #pragma unroll
    for (int m = 0; m < MMOD; ++m)
      if (s >= offs[m] && s < ends[m]) f = 1;
    tot += f;
    lc[i] = tot;
  }
  int v = tot;
  #pragma unroll
  for (int o = 1; o < 64; o <<= 1) {
    int u = __shfl_up(v, o);
    if (lane >= o) v += u;
  }
  int excl = v - tot;
  #pragma unroll
  for (int i = 0; i < NN / 64; ++i)
    pos[bb * NN + base + i] = base + i - (excl + lc[i]);
}

// ---------------------------------------------------------------------------
// K2b: RoPE cos/sin table [b*n][32] float2
// ---------------------------------------------------------------------------
__global__ void k_tab(const int* __restrict__ pos, float2* __restrict__ tab) {
  int gid = blockIdx.x * 256 + threadIdx.x;   // b*n*32 = 131072
  int p = gid & 31;
  int bs = gid >> 5;
  float inv = expf(-((float)p / 32.f) * 9.210340371976184f); // 1/10000^(2p/64)
  float ang = (float)pos[bs] * inv;
  float sn, cs;
  sincosf(ang, &sn, &cs);
  tab[gid] = make_float2(cs, sn);
}

// ---------------------------------------------------------------------------
// K3: transpose f32 [R][C] -> bf16 [C][R]
// ---------------------------------------------------------------------------
__global__ void k_tr(const float* __restrict__ in, unsigned short* __restrict__ out,
                     int R, int C) {
  __shared__ float tile[32][33];
  int bx = blockIdx.x, by = blockIdx.y;
  int tx = threadIdx.x, ty = threadIdx.y;
  #pragma unroll
  for (int k = 0; k < 4; ++k) {
    int r = by * 32 + ty + k * 8, c = bx * 32 + tx;
    tile[ty + k * 8][tx] = in[(size_t)r * C + c];
  }
  __syncthreads();
  #pragma unroll
  for (int k = 0; k < 4; ++k) {
    int oc = bx * 32 + ty + k * 8;
    int orr = by * 32 + tx;
    out[(size_t)oc * R + orr] = f2bf(tile[tx][ty + k * 8]);
  }
}

// ---------------------------------------------------------------------------
// K4: QKV GEMM 128x128, BK=64, 4 waves, dbuf LDS + XOR swz + XCD swizzle.
// ---------------------------------------------------------------------------
template<bool F32OUT>
__global__ __launch_bounds__(256) void k_gemm(const unsigned short* __restrict__ A,
                                              const unsigned short* __restrict__ Bt,
                                              void* __restrict__ Cp,
                                              int M, int Nn, int K) {
  __shared__ unsigned short As[2][128 * 64];
  __shared__ unsigned short Bs[2][128 * 64];
  int tid = threadIdx.x;
  int lane = tid & 63, wv = tid >> 6;
  int lo = lane & 15, hi = lane >> 4;
  int nb = gridDim.x * gridDim.y;
  int fid = blockIdx.y * gridDim.x + blockIdx.x;
  int cpx = nb >> 3;
  int nid = (fid & 7) * cpx + (fid >> 3);      // contiguous chunk per XCD
  int m0 = (nid / gridDim.x) * 128;
  int n0 = (nid % gridDim.x) * 128;
  int wr = wv >> 1, wc = wv & 1;
  f32x4 acc[4][4] = {};

  int srow = tid >> 3;
  int scs  = ((tid & 7) ^ ((tid >> 3) & 7)) * 8;
  #define STAGE_G(BUF, KT) do { \
    _Pragma("unroll") \
    for (int is_ = 0; is_ < 4; ++is_) { \
      int r_ = is_ * 32 + srow; \
      const unsigned short* ga_ = A  + (size_t)(m0 + r_) * K + (KT) + scs; \
      const unsigned short* gb_ = Bt + (size_t)(n0 + r_) * K + (KT) + scs; \
      ASYNC_LDS16(ga_, &As[BUF][(is_ * 256 + wv * 64) * 8]); \
      ASYNC_LDS16(gb_, &Bs[BUF][(is_ * 256 + wv * 64) * 8]); \
    } \
  } while (0)

  int nt = K >> 6;
  STAGE_G(0, 0);
  __syncthreads();
  int buf = 0;
  for (int t = 0; t < nt; ++t) {
    if (t + 1 < nt) STAGE_G(buf ^ 1, (t + 1) << 6);
    #pragma unroll
    for (int ks = 0; ks < 2; ++ks) {
      s16x8 af[4], bfr[4];
      #pragma unroll
      for (int m = 0; m < 4; ++m) {
        int row = wr * 64 + m * 16 + lo;
        int cc = ((ks * 4 + hi) ^ (lo & 7)) * 8;
        af[m] = *(const s16x8*)&As[buf][row * 64 + cc];
      }
      #pragma unroll
      for (int nn = 0; nn < 4; ++nn) {
        int row = wc * 64 + nn * 16 + lo;
        int cc = ((ks * 4 + hi) ^ (lo & 7)) * 8;
        bfr[nn] = *(const s16x8*)&Bs[buf][row * 64 + cc];
      }
      #pragma unroll
      for (int m = 0; m < 4; ++m)
        #pragma unroll
        for (int nn = 0; nn < 4; ++nn)
          acc[m][nn] = __builtin_amdgcn_mfma_f32_16x16x32_bf16(af[m], bfr[nn], acc[m][nn], 0, 0, 0);
    }
    __syncthreads();
    buf ^= 1;
  }
  #undef STAGE_G

  #pragma unroll
  for (int m = 0; m < 4; ++m) {
    #pragma unroll
    for (int nn = 0; nn < 4; ++nn) {
      int r0 = m0 + wr * 64 + m * 16 + hi * 4;
      int cc = n0 + wc * 64 + nn * 16 + lo;
      #pragma unroll
      for (int j = 0; j < 4; ++j) {
        float val = acc[m][nn][j];
        if (F32OUT) ((float*)Cp)[(size_t)(r0 + j) * Nn + cc] = val;
        else        ((unsigned short*)Cp)[(size_t)(r0 + j) * Nn + cc] = f2bf(val);
      }
    }
  }
}

// ---------------------------------------------------------------------------
// K7: out-proj GEMM, BM=128 BN=64 (grid 512), 4 waves stacked, acc[2][4].
// ---------------------------------------------------------------------------
template<bool F32OUT>
__global__ __launch_bounds__(256) void k_gemm_n64(const unsigned short* __restrict__ A,
                                                  const unsigned short* __restrict__ Bt,
                                                  void* __restrict__ Cp,
                                                  int M, int Nn, int K) {
  __shared__ unsigned short As[2][128 * 64];
  __shared__ unsigned short Bs[2][64 * 64];
  int tid = threadIdx.x;
  int lane = tid & 63, wv = tid >> 6;
  int lo = lane & 15, hi = lane >> 4;
  int nb = gridDim.x * gridDim.y;
  int fid = blockIdx.y * gridDim.x + blockIdx.x;
  int cpx = nb >> 3;
  int nid = (fid & 7) * cpx + (fid >> 3);
  int m0 = (nid / gridDim.x) * 128;
  int n0 = (nid % gridDim.x) * 64;
  f32x4 acc[2][4] = {};

  int srow = tid >> 3;
  int scs  = ((tid & 7) ^ ((tid >> 3) & 7)) * 8;
  #define STAGE_N(BUF, KT) do { \
    _Pragma("unroll") \
    for (int is_ = 0; is_ < 4; ++is_) { \
      int r_ = is_ * 32 + srow; \
      const unsigned short* ga_ = A + (size_t)(m0 + r_) * K + (KT) + scs; \
      ASYNC_LDS16(ga_, &As[BUF][(is_ * 256 + wv * 64) * 8]); \
    } \
    _Pragma("unroll") \
    for (int is_ = 0; is_ < 2; ++is_) { \
      int r_ = is_ * 32 + srow; \
      const unsigned short* gb_ = Bt + (size_t)(n0 + r_) * K + (KT) + scs; \
      ASYNC_LDS16(gb_, &Bs[BUF][(is_ * 256 + wv * 64) * 8]); \
    } \
  } while (0)

  int nt = K >> 6;
  STAGE_N(0, 0);
  __syncthreads();
  int buf = 0;
  for (int t = 0; t < nt; ++t) {
    if (t + 1 < nt) STAGE_N(buf ^ 1, (t + 1) << 6);
    #pragma unroll
    for (int ks = 0; ks < 2; ++ks) {
      s16x8 af[2], bfr[4];
      #pragma unroll
      for (int m = 0; m < 2; ++m) {
        int row = wv * 32 + m * 16 + lo;
        int cc = ((ks * 4 + hi) ^ (lo & 7)) * 8;
        af[m] = *(const s16x8*)&As[buf][row * 64 + cc];
      }
      #pragma unroll
      for (int nn = 0; nn < 4; ++nn) {
        int row = nn * 16 + lo;
        int cc = ((ks * 4 + hi) ^ (lo & 7)) * 8;
        bfr[nn] = *(const s16x8*)&Bs[buf][row * 64 + cc];
      }
      #pragma unroll
      for (int m = 0; m < 2; ++m)
        #pragma unroll
        for (int nn = 0; nn < 4; ++nn)
          acc[m][nn] = __builtin_amdgcn_mfma_f32_16x16x32_bf16(af[m], bfr[nn], acc[m][nn], 0, 0, 0);
    }
    __syncthreads();
    buf ^= 1;
  }
  #undef STAGE_N

  #pragma unroll
  for (int m = 0; m < 2; ++m)
    #pragma unroll
    for (int nn = 0; nn < 4; ++nn) {
      int r0 = m0 + wv * 32 + m * 16 + hi * 4;
      int cc = n0 + nn * 16 + lo;
      #pragma unroll
      for (int j = 0; j < 4; ++j) {
        float val = acc[m][nn][j];
        if (F32OUT) ((float*)Cp)[(size_t)(r0 + j) * Nn + cc] = val;
        else        ((unsigned short*)Cp)[(size_t)(r0 + j) * Nn + cc] = f2bf(val);
      }
    }
}

// ---------------------------------------------------------------------------
// K5: RoPE apply for K only: qkvt cols 1024..2047 -> kd [b*H][n][64] bf16
// ---------------------------------------------------------------------------
__global__ __launch_bounds__(256) void k_rope(const unsigned short* __restrict__ qkv,
                                              const float2* __restrict__ tab,
                                              unsigned short* __restrict__ k) {
  int bs = blockIdx.x;
  int bb = bs / NN, s = bs % NN;
  int lane = threadIdx.x & 63, wv = threadIdx.x >> 6;
  #pragma unroll
  for (int g = 16 + wv; g < 32; g += 4) {
    int h = g & 15;
    float val = bf2f(qkv[(size_t)bs * QKVN + g * 64 + lane]);
    float partner = __shfl_xor(val, 1);
    float2 cs = tab[(size_t)bs * 32 + (lane >> 1)];
    float out;
    if ((lane & 1) == 0) out = val * cs.x - partner * cs.y;      // t1*cos - t2*sin
    else                 out = partner * cs.y + val * cs.x;      // t1*sin + t2*cos
    k[((size_t)(bb * HH + h) * NN + s) * 64 + lane] = f2bf(out);
  }
}

// ---------------------------------------------------------------------------
// K5b: V transpose + PV slot-permutation (sigma2 = swap key bits 2<->3):
// qkvt[.][2048+h*64+dh] -> vT[bh][dh][64t + sigma2(key%64)]
// ---------------------------------------------------------------------------
__global__ __launch_bounds__(256) void k_vtr(const unsigned short* __restrict__ qkvt,
                                             unsigned short* __restrict__ vT) {
  __shared__ unsigned short t[64][72];
  int s0 = blockIdx.x * 64, bh = blockIdx.y, bb = bh >> 4, h = bh & 15;
  int tid = threadIdx.x;
  int r = tid >> 2, c0 = (tid & 3) * 16;
  int cw = c0 ^ (((r >> 4) & 3) << 4);
  const unsigned short* src = qkvt + (size_t)(bb * NN + s0 + r) * QKVN + 2048 + h * 64 + c0;
  *(s16x8*)&t[r][cw]     = *(const s16x8*)src;
  *(s16x8*)&t[r][cw + 8] = *(const s16x8*)(src + 8);
  __syncthreads();
  int dh = tid >> 2, sc = (tid & 3) * 16;
  int col2 = dh ^ ((tid & 3) << 4);
  s16x8 o1, o2;
  #pragma unroll
  for (int i = 0; i < 8; ++i) {
    o1[i] = (short)t[sc + i][col2];       // keys sc+i   (bit3=0)
    o2[i] = (short)t[sc + 8 + i][col2];   // keys sc+8+i (bit3=1)
  }
  unsigned short* dst = vT + ((size_t)bh * 64 + dh) * NN + s0 + sc;
  // sigma2: key bits b2<->b3. o1 i=0..3 -> +0..3; i=4..7 -> +8..11;
  //                           o2 i=0..3 -> +4..7; i=4..7 -> +12..15.
  s16x4 g0 = __builtin_shufflevector(o1, o1, 0, 1, 2, 3);
  s16x4 g1 = __builtin_shufflevector(o1, o1, 4, 5, 6, 7);
  s16x4 g2 = __builtin_shufflevector(o2, o2, 0, 1, 2, 3);
  s16x4 g3 = __builtin_shufflevector(o2, o2, 4, 5, 6, 7);
  *(s16x4*)&dst[0]  = g0;
  *(s16x4*)&dst[8]  = g1;
  *(s16x4*)&dst[4]  = g2;
  *(s16x4*)&dst[12] = g3;
}

// ---------------------------------------------------------------------------
// K6: flash attention, 32x32x16 MFMA (2x flops per LDS byte), 4 waves x
// 32 q-rows (waves 0-1 long 64-row tile, 2-3 mirror short tile), KVBLK=64
// dbuf staging, in-register Q-RoPE, lane-local P via sigma2-permuted vT.
// ---------------------------------------------------------------------------
__global__ __launch_bounds__(256) void k_attn(const unsigned short* __restrict__ qkvt,
                                              const float2* __restrict__ tab,
                                              const unsigned short* __restrict__ k,
                                              const unsigned short* __restrict__ vT,
                                              const int* __restrict__ mods,
                                              unsigned short* __restrict__ o) {
  __shared__ unsigned short Ks[2][64 * 64];
  __shared__ unsigned short Vs[2][64 * 64];
  int tid = threadIdx.x;
  int lane = tid & 63, wv = tid >> 6;        // 4 waves
  int l31 = lane & 31, L = lane >> 5;

  int fid = blockIdx.y * gridDim.x + blockIdx.x;      // 0..511
  int nid = (fid & 7) * 64 + (fid >> 3);              // XCD-contiguous
  int bh = nid >> 4;
  int bx = nid & 15;
  int bb = bh >> 4;
  int h = bh & 15;
  int q0A = (31 - bx) * 64;                           // long tile
  int q0B = bx * 64;                                  // mirror short tile
  int q0w = ((wv < 2) ? q0A : q0B) + (wv & 1) * 32;   // 32 rows per wave

  const unsigned short* kb = k + (size_t)bh * NN * 64;
  const unsigned short* vb = vT + (size_t)bh * 64 * NN;

  // Q fragments (B operand, 32x32x16): qrow = q0w + l31,
  // qf[kc] = Q[qrow][kc*16 + L*8 .. +8], RoPE applied in-register.
  s16x8 qf[4];
  {
    int qrow = q0w + l31;
    const unsigned short* qp = qkvt + (size_t)(bb * NN + qrow) * QKVN + h * 64;
    const float2* tb = tab + (size_t)(bb * NN + qrow) * 32;
    #pragma unroll
    for (int kc = 0; kc < 4; ++kc) {
      s16x8 raw = *(const s16x8*)&qp[kc * 16 + L * 8];
      #pragma unroll
      for (int e2 = 0; e2 < 4; ++e2) {
        float2 cs = tb[kc * 8 + L * 4 + e2];
        float t1 = bf2f((unsigned short)raw[2 * e2]);
        float t2 = bf2f((unsigned short)raw[2 * e2 + 1]);
        float o1 = (t1 * cs.x - t2 * cs.y) * 0.18033688011112042f; // 0.125*log2e
        float o2 = (t1 * cs.y + t2 * cs.x) * 0.18033688011112042f;
        qf[kc][2 * e2]     = (short)f2bf(o1);
        qf[kc][2 * e2 + 1] = (short)f2bf(o2);
      }
    }
  }

  int off_[MMOD], end_[MMOD];
  #pragma unroll
  for (int m = 0; m < MMOD; ++m) {
    off_[m] = mods[(bb * MMOD + m) * 3 + 1];
    end_[m] = off_[m] + mods[(bb * MMOD + m) * 3 + 2];
  }
  int limit_l;
  {
    int r = q0w + l31;
    int Lm = r + 1;
    #pragma unroll
    for (int m = 0; m < MMOD; ++m)
      if (off_[m] <= r && end_[m] > Lm) Lm = end_[m];
    limit_l = Lm;
  }
  int minlim, kvmax_w;
  {
    int Lm = q0w + 1;
    #pragma unroll
    for (int m = 0; m < MMOD; ++m)
      if (off_[m] <= q0w && end_[m] > Lm) Lm = end_[m];
    minlim = Lm;
    int r = q0w + 31;
    int L2 = r + 1;
    #pragma unroll
    for (int m = 0; m < MMOD; ++m)
      if (off_[m] <= r && end_[m] > L2) L2 = end_[m];
    kvmax_w = L2;
  }
  int nt;
  {
    int ra = q0A + 63;
    int LA = ra + 1;
    #pragma unroll
    for (int m = 0; m < MMOD; ++m)
      if (off_[m] <= ra && end_[m] > LA) LA = end_[m];
    int rb2 = q0B + 63;
    int LB = rb2 + 1;
    #pragma unroll
    for (int m = 0; m < MMOD; ++m)
      if (off_[m] <= rb2 && end_[m] > LB) LB = end_[m];
    int Lblk = (LA > LB) ? LA : LB;
    nt = (Lblk + 63) >> 6;
  }

  // 256 threads stage K (64x64) and V (64x64) tiles, 2 x 16B chunks each.
  #define STAGE_KV(B, KV0) do { \
    _Pragma("unroll") \
    for (int i_ = 0; i_ < 2; ++i_) { \
      int r_ = i_ * 32 + (tid >> 3); \
      int cs_ = (tid & 7) ^ ((tid >> 3) & 7); \
      const unsigned short* gK_ = kb + (size_t)((KV0) + r_) * 64 + cs_ * 8; \
      ASYNC_LDS16(gK_, &Ks[B][(i_ * 256 + wv * 64) * 8]); \
      const unsigned short* gV_ = vb + (size_t)r_ * NN + (KV0) + cs_ * 8; \
      ASYNC_LDS16(gV_, &Vs[B][(i_ * 256 + wv * 64) * 8]); \
    } \
  } while (0)

  float lr = 0.f;
  f32x16 accO0 = {}, accO1 = {};

  STAGE_KV(0, 0);
  __syncthreads();
  int buf = 0;
  for (int t = 0; t < nt; ++t) {
    if (t + 1 < nt) STAGE_KV(buf ^ 1, (t + 1) << 6);
    int kv0 = t << 6;
    if (kv0 < kvmax_w) {
      // S^T: D[key][qrow], col=lane&31=qrow, key=(reg&3)+8*(reg>>2)+4L+32g
      f32x16 sv0 = {}, sv1 = {};
      __builtin_amdgcn_s_setprio(1);
      #pragma unroll
      for (int kc = 0; kc < 4; ++kc) {
        int cp = ((kc * 2 + L) ^ (lane & 7)) * 8;
        s16x8 kf0 = *(const s16x8*)&Ks[buf][(l31) * 64 + cp];
        s16x8 kf1 = *(const s16x8*)&Ks[buf][(32 + l31) * 64 + cp];
        sv0 = __builtin_amdgcn_mfma_f32_32x32x16_bf16(kf0, qf[kc], sv0, 0, 0, 0);
        sv1 = __builtin_amdgcn_mfma_f32_32x32x16_bf16(kf1, qf[kc], sv1, 0, 0, 0);
      }
      __builtin_amdgcn_s_setprio(0);

      // p = exp2(s - s^3*k2); e^-50 shift cancels in normalization
      float pr0[16], pr1[16];
      bool edge = (kv0 + 64 > minlim);
      int kbase = kv0 + 4 * L;
      #pragma unroll
      for (int r = 0; r < 16; ++r) {
        int koff = (r & 3) + 8 * (r >> 2);
        {
          float s = sv0[r];
          float u = __builtin_fmaf(s * s, -6.40604e-5f, 1.0f);
          float pp = __builtin_amdgcn_exp2f(s * u);
          if (edge && (kbase + koff) >= limit_l) pp = 0.f;
          lr += pp;
          pr0[r] = pp;
        }
        {
          float s = sv1[r];
          float u = __builtin_fmaf(s * s, -6.40604e-5f, 1.0f);
          float pp = __builtin_amdgcn_exp2f(s * u);
          if (edge && (kbase + 32 + koff) >= limit_l) pp = 0.f;
          lr += pp;
          pr1[r] = pp;
        }
      }

      // pa[kc2][e] = p_{g=kc2>>1}[e + 8*(kc2&1)]  (sigma2 alignment)
      union { unsigned int u[4]; s16x8 v; } pa[4];
      #pragma unroll
      for (int w = 0; w < 4; ++w) {
        pa[0].u[w] = cvt_pk_bf16(pr0[2 * w],     pr0[2 * w + 1]);
        pa[1].u[w] = cvt_pk_bf16(pr0[8 + 2 * w], pr0[8 + 2 * w + 1]);
        pa[2].u[w] = cvt_pk_bf16(pr1[2 * w],     pr1[2 * w + 1]);
        pa[3].u[w] = cvt_pk_bf16(pr1[8 + 2 * w], pr1[8 + 2 * w + 1]);
      }

      // PV: accO[go] += P x V^T, B operand from sigma2-slot LDS
      __builtin_amdgcn_s_setprio(1);
      #pragma unroll
      for (int kc2 = 0; kc2 < 4; ++kc2) {
        int cp = ((kc2 * 2 + L) ^ (lane & 7)) * 8;
        s16x8 vf0 = *(const s16x8*)&Vs[buf][(l31) * 64 + cp];
        s16x8 vf1 = *(const s16x8*)&Vs[buf][(32 + l31) * 64 + cp];
        accO0 = __builtin_amdgcn_mfma_f32_32x32x16_bf16(pa[kc2].v, vf0, accO0, 0, 0, 0);
        accO1 = __builtin_amdgcn_mfma_f32_32x32x16_bf16(pa[kc2].v, vf1, accO1, 0, 0, 0);
      }
      __builtin_amdgcn_s_setprio(0);
    }
    __syncthreads();
    buf ^= 1;
  }

  // denominator: lane holds half of qrow=l31's keys; combine across L halves
  lr += __shfl_xor(lr, 32);
  float rl[16];
  #pragma unroll
  for (int r = 0; r < 16; ++r) {
    int rw = (r & 3) + 8 * (r >> 2) + 4 * L;
    rl[r] = __builtin_amdgcn_rcpf(__shfl(lr, rw));
  }

  #pragma unroll
  for (int r = 0; r < 16; ++r) {
    int rw = (r & 3) + 8 * (r >> 2) + 4 * L;
    int rout = q0w + rw;
    size_t base = ((size_t)(bb * NN) + rout) * (HH * DHD) + h * 64;
    o[base + l31]      = f2bf(accO0[r] * rl[r]);
    o[base + 32 + l31] = f2bf(accO1[r] * rl[r]);
  }
}

// ---------------------------------------------------------------------------
extern "C" void kernel_launch(void* const* d_in, const int* in_sizes, int n_in,
                              void* d_out, int out_size, void* d_ws, size_t ws_size,
                              hipStream_t stream) {
  (void)in_sizes; (void)n_in; (void)out_size; (void)ws_size;
  const float* x      = (const float*)d_in[0];
  const float* tokens = (const float*)d_in[1];
  const float* gamma  = (const float*)d_in[2];
  const float* w_qkv  = (const float*)d_in[3];
  const float* w_out  = (const float*)d_in[4];
  const int*   mods   = (const int*)d_in[5];

  char* ws = (char*)d_ws;
  unsigned short* xn    = (unsigned short*)(ws + 0);           //  8 MB
  unsigned short* wqkvT = (unsigned short*)(ws + 8388608);     //  6 MB
  unsigned short* woutT = (unsigned short*)(ws + 14680064);    //  2 MB
  unsigned short* qkvt  = (unsigned short*)(ws + 16777216);    // 24 MB
  unsigned short* kd    = (unsigned short*)(ws + 50331648);    //  8 MB
  unsigned short* vTd   = (unsigned short*)(ws + 58720256);    //  8 MB
  unsigned short* attno = (unsigned short*)(ws + 67108864);    //  8 MB
  int*            pos   = (int*)(ws + 75497472);               // 16 KB
  float2*         tab   = (float2*)(ws + 75513856);            //  1 MB

  k_prep<<<BNROWS, 256, 0, stream>>>(x, tokens, gamma, mods, xn);
  k_pos<<<BB, 64, 0, stream>>>(mods, pos);
  k_tab<<<(BB * NN * 32) / 256, 256, 0, stream>>>(pos, tab);
  k_tr<<<dim3(QKVN / 32, DD / 32), dim3(32, 8), 0, stream>>>(w_qkv, wqkvT, DD, QKVN);
  k_tr<<<dim3((HH * DHD) / 32, DD / 32), dim3(32, 8), 0, stream>>>(w_out, woutT, HH * DHD, DD);
  k_gemm<false><<<dim3(QKVN / 128, BNROWS / 128), 256, 0, stream>>>(xn, wqkvT, (void*)qkvt, BNROWS, QKVN, DD);
  k_rope<<<BNROWS, 256, 0, stream>>>(qkvt, tab, kd);
  k_vtr<<<dim3(NN / 64, BB * HH), 256, 0, stream>>>(qkvt, vTd);
  k_attn<<<dim3(16, BB * HH), 256, 0, stream>>>(qkvt, tab, kd, vTd, mods, attno);
  k_gemm_n64<true><<<dim3(DD / 64, BNROWS / 128), 256, 0, stream>>>(attno, woutT, (void*)d_out, BNROWS, DD, HH * DHD);
}

// Round 16
// 142.363 us; speedup vs baseline: 1.0739x; 1.0739x over previous
//
#include <hip/hip_runtime.h>
#include <stdint.h>

#define HH 16
#define DHD 64
#define BB 2
#define NN 2048
#define DD 1024
#define MMOD 4
#define LMAX 256
#define BNROWS (BB*NN)      // 4096
#define QKVN (3*HH*DHD)     // 3072

typedef __attribute__((ext_vector_type(4))) float f32x4;
typedef __attribute__((ext_vector_type(8))) short s16x8;
typedef __attribute__((ext_vector_type(4))) short s16x4;

__device__ __forceinline__ float bf2f(unsigned short b) {
  return __uint_as_float(((unsigned int)b) << 16);
}
__device__ __forceinline__ unsigned short f2bf(float f) {
  unsigned int u = __float_as_uint(f);
  u += 0x7fffu + ((u >> 16) & 1u);
  return (unsigned short)(u >> 16);
}
__device__ __forceinline__ unsigned int cvt_pk_bf16(float a, float b) {
  unsigned int r;
  asm("v_cvt_pk_bf16_f32 %0, %1, %2" : "=v"(r) : "v"(a), "v"(b));
  return r;
}

#define ASYNC_LDS16(g, l) \
  __builtin_amdgcn_global_load_lds((const __attribute__((address_space(1))) void*)(g), \
                                   (__attribute__((address_space(3))) void*)(l), 16, 0, 0)

// ---------------------------------------------------------------------------
// K1: modality splice + norm + gamma, write xn bf16 [4096][1024]
// ---------------------------------------------------------------------------
__global__ __launch_bounds__(256) void k_prep(const float* __restrict__ x,
                                              const float* __restrict__ tokens,
                                              const float* __restrict__ gamma,
                                              const int* __restrict__ mods,
                                              unsigned short* __restrict__ xn) {
  int bs = blockIdx.x;
  int bb = bs / NN, s = bs % NN;
  int t = threadIdx.x;
  int c = t * 4;
  const float4 xv = *(const float4*)(x + (size_t)bs * DD + c);
  float4 acc = {0.f, 0.f, 0.f, 0.f};
  bool any = false;
  #pragma unroll
  for (int m = 0; m < MMOD; ++m) {
    int off = mods[(bb * MMOD + m) * 3 + 1];
    int ln  = mods[(bb * MMOD + m) * 3 + 2];
    if (s >= off && s < off + ln) {
      any = true;
      int rel = s - off;
      if (rel > LMAX - 1) rel = LMAX - 1;
      if (rel < 0) rel = 0;
      const float4 tv = *(const float4*)(tokens + ((size_t)(bb * MMOD + m) * LMAX + rel) * DD + c);
      acc.x += tv.x; acc.y += tv.y; acc.z += tv.z; acc.w += tv.w;
    }
  }
  float4 v = any ? acc : xv;
  float ss = v.x*v.x + v.y*v.y + v.z*v.z + v.w*v.w;
  #pragma unroll
  for (int o = 32; o; o >>= 1) ss += __shfl_xor(ss, o);
  __shared__ float red[4];
  int wv = t >> 6;
  if ((t & 63) == 0) red[wv] = ss;
  __syncthreads();
  float tot = red[0] + red[1] + red[2] + red[3];
  float norm = sqrtf(tot);
  norm = fmaxf(norm, 1e-12f);
  float sc = 32.0f / norm;   // sqrt(1024) = 32
  const float4 g = *(const float4*)(gamma + c);
  unsigned long long pk =
      (unsigned long long)f2bf(v.x * sc * (g.x + 1.f)) |
      ((unsigned long long)f2bf(v.y * sc * (g.y + 1.f)) << 16) |
      ((unsigned long long)f2bf(v.z * sc * (g.z + 1.f)) << 32) |
      ((unsigned long long)f2bf(v.w * sc * (g.w + 1.f)) << 48);
  *(unsigned long long*)(xn + (size_t)bs * DD + c) = pk;
}

// ---------------------------------------------------------------------------
// K2: pos[b][n] = s - cumsum(rot_any). One wave per batch.
// ---------------------------------------------------------------------------
__global__ void k_pos(const int* __restrict__ mods, int* __restrict__ pos) {
  int bb = blockIdx.x;
  int lane = threadIdx.x;       // 64
  int offs[MMOD], ends[MMOD];
  #pragma unroll
  for (int m = 0; m < MMOD; ++m) {
    int off = mods[(bb * MMOD + m) * 3 + 1];
    int ln  = mods[(bb * MMOD + m) * 3 + 2];
    offs[m] = off + 1;
    ends[m] = off + ln;
  }
  int base = lane * (NN / 64);  // 32 per lane
  int lc[NN / 64];
  int tot = 0;
  #pragma unroll
  for (int i = 0; i < NN / 64; ++i) {
    int s = base + i;
    int f = 0;
    #pragma unroll
    for (int m = 0; m < MMOD; ++m)
      if (s >= offs[m] && s < ends[m]) f = 1;
    tot += f;
    lc[i] = tot;
  }
  int v = tot;
  #pragma unroll
  for (int o = 1; o < 64; o <<= 1) {
    int u = __shfl_up(v, o);
    if (lane >= o) v += u;
  }
  int excl = v - tot;
  #pragma unroll
  for (int i = 0; i < NN / 64; ++i)
    pos[bb * NN + base + i] = base + i - (excl + lc[i]);
}

// ---------------------------------------------------------------------------
// K2b: RoPE cos/sin table [b*n][32] float2
// ---------------------------------------------------------------------------
__global__ void k_tab(const int* __restrict__ pos, float2* __restrict__ tab) {
  int gid = blockIdx.x * 256 + threadIdx.x;   // b*n*32 = 131072
  int p = gid & 31;
  int bs = gid >> 5;
  float inv = expf(-((float)p / 32.f) * 9.210340371976184f); // 1/10000^(2p/64)
  float ang = (float)pos[bs] * inv;
  float sn, cs;
  sincosf(ang, &sn, &cs);
  tab[gid] = make_float2(cs, sn);
}

// ---------------------------------------------------------------------------
// K3: transpose f32 [R][C] -> bf16 [C][R]
// ---------------------------------------------------------------------------
__global__ void k_tr(const float* __restrict__ in, unsigned short* __restrict__ out,
                     int R, int C) {
  __shared__ float tile[32][33];
  int bx = blockIdx.x, by = blockIdx.y;
  int tx = threadIdx.x, ty = threadIdx.y;
  #pragma unroll
  for (int k = 0; k < 4; ++k) {
    int r = by * 32 + ty + k * 8, c = bx * 32 + tx;
    tile[ty + k * 8][tx] = in[(size_t)r * C + c];
  }
  __syncthreads();
  #pragma unroll
  for (int k = 0; k < 4; ++k) {
    int oc = bx * 32 + ty + k * 8;
    int orr = by * 32 + tx;
    out[(size_t)oc * R + orr] = f2bf(tile[tx][ty + k * 8]);
  }
}

// ---------------------------------------------------------------------------
// K4: QKV GEMM 128x128, BK=64, 4 waves, dbuf LDS + XOR swz + XCD swizzle.
// ---------------------------------------------------------------------------
template<bool F32OUT>
__global__ __launch_bounds__(256) void k_gemm(const unsigned short* __restrict__ A,
                                              const unsigned short* __restrict__ Bt,
                                              void* __restrict__ Cp,
                                              int M, int Nn, int K) {
  __shared__ unsigned short As[2][128 * 64];
  __shared__ unsigned short Bs[2][128 * 64];
  int tid = threadIdx.x;
  int lane = tid & 63, wv = tid >> 6;
  int lo = lane & 15, hi = lane >> 4;
  int nb = gridDim.x * gridDim.y;
  int fid = blockIdx.y * gridDim.x + blockIdx.x;
  int cpx = nb >> 3;
  int nid = (fid & 7) * cpx + (fid >> 3);      // contiguous chunk per XCD
  int m0 = (nid / gridDim.x) * 128;
  int n0 = (nid % gridDim.x) * 128;
  int wr = wv >> 1, wc = wv & 1;
  f32x4 acc[4][4] = {};

  int srow = tid >> 3;
  int scs  = ((tid & 7) ^ ((tid >> 3) & 7)) * 8;
  #define STAGE_G(BUF, KT) do { \
    _Pragma("unroll") \
    for (int is_ = 0; is_ < 4; ++is_) { \
      int r_ = is_ * 32 + srow; \
      const unsigned short* ga_ = A  + (size_t)(m0 + r_) * K + (KT) + scs; \
      const unsigned short* gb_ = Bt + (size_t)(n0 + r_) * K + (KT) + scs; \
      ASYNC_LDS16(ga_, &As[BUF][(is_ * 256 + wv * 64) * 8]); \
      ASYNC_LDS16(gb_, &Bs[BUF][(is_ * 256 + wv * 64) * 8]); \
    } \
  } while (0)

  int nt = K >> 6;
  STAGE_G(0, 0);
  __syncthreads();
  int buf = 0;
  for (int t = 0; t < nt; ++t) {
    if (t + 1 < nt) STAGE_G(buf ^ 1, (t + 1) << 6);
    #pragma unroll
    for (int ks = 0; ks < 2; ++ks) {
      s16x8 af[4], bfr[4];
      #pragma unroll
      for (int m = 0; m < 4; ++m) {
        int row = wr * 64 + m * 16 + lo;
        int cc = ((ks * 4 + hi) ^ (lo & 7)) * 8;
        af[m] = *(const s16x8*)&As[buf][row * 64 + cc];
      }
      #pragma unroll
      for (int nn = 0; nn < 4; ++nn) {
        int row = wc * 64 + nn * 16 + lo;
        int cc = ((ks * 4 + hi) ^ (lo & 7)) * 8;
        bfr[nn] = *(const s16x8*)&Bs[buf][row * 64 + cc];
      }
      #pragma unroll
      for (int m = 0; m < 4; ++m)
        #pragma unroll
        for (int nn = 0; nn < 4; ++nn)
          acc[m][nn] = __builtin_amdgcn_mfma_f32_16x16x32_bf16(af[m], bfr[nn], acc[m][nn], 0, 0, 0);
    }
    __syncthreads();
    buf ^= 1;
  }
  #undef STAGE_G

  #pragma unroll
  for (int m = 0; m < 4; ++m) {
    #pragma unroll
    for (int nn = 0; nn < 4; ++nn) {
      int r0 = m0 + wr * 64 + m * 16 + hi * 4;
      int cc = n0 + wc * 64 + nn * 16 + lo;
      #pragma unroll
      for (int j = 0; j < 4; ++j) {
        float val = acc[m][nn][j];
        if (F32OUT) ((float*)Cp)[(size_t)(r0 + j) * Nn + cc] = val;
        else        ((unsigned short*)Cp)[(size_t)(r0 + j) * Nn + cc] = f2bf(val);
      }
    }
  }
}

// ---------------------------------------------------------------------------
// K7: out-proj GEMM, BM=128 BN=64 (grid 512), 4 waves stacked, acc[2][4].
// ---------------------------------------------------------------------------
template<bool F32OUT>
__global__ __launch_bounds__(256) void k_gemm_n64(const unsigned short* __restrict__ A,
                                                  const unsigned short* __restrict__ Bt,
                                                  void* __restrict__ Cp,
                                                  int M, int Nn, int K) {
  __shared__ unsigned short As[2][128 * 64];
  __shared__ unsigned short Bs[2][64 * 64];
  int tid = threadIdx.x;
  int lane = tid & 63, wv = tid >> 6;
  int lo = lane & 15, hi = lane >> 4;
  int nb = gridDim.x * gridDim.y;
  int fid = blockIdx.y * gridDim.x + blockIdx.x;
  int cpx = nb >> 3;
  int nid = (fid & 7) * cpx + (fid >> 3);
  int m0 = (nid / gridDim.x) * 128;
  int n0 = (nid % gridDim.x) * 64;
  f32x4 acc[2][4] = {};

  int srow = tid >> 3;
  int scs  = ((tid & 7) ^ ((tid >> 3) & 7)) * 8;
  #define STAGE_N(BUF, KT) do { \
    _Pragma("unroll") \
    for (int is_ = 0; is_ < 4; ++is_) { \
      int r_ = is_ * 32 + srow; \
      const unsigned short* ga_ = A + (size_t)(m0 + r_) * K + (KT) + scs; \
      ASYNC_LDS16(ga_, &As[BUF][(is_ * 256 + wv * 64) * 8]); \
    } \
    _Pragma("unroll") \
    for (int is_ = 0; is_ < 2; ++is_) { \
      int r_ = is_ * 32 + srow; \
      const unsigned short* gb_ = Bt + (size_t)(n0 + r_) * K + (KT) + scs; \
      ASYNC_LDS16(gb_, &Bs[BUF][(is_ * 256 + wv * 64) * 8]); \
    } \
  } while (0)

  int nt = K >> 6;
  STAGE_N(0, 0);
  __syncthreads();
  int buf = 0;
  for (int t = 0; t < nt; ++t) {
    if (t + 1 < nt) STAGE_N(buf ^ 1, (t + 1) << 6);
    #pragma unroll
    for (int ks = 0; ks < 2; ++ks) {
      s16x8 af[2], bfr[4];
      #pragma unroll
      for (int m = 0; m < 2; ++m) {
        int row = wv * 32 + m * 16 + lo;
        int cc = ((ks * 4 + hi) ^ (lo & 7)) * 8;
        af[m] = *(const s16x8*)&As[buf][row * 64 + cc];
      }
      #pragma unroll
      for (int nn = 0; nn < 4; ++nn) {
        int row = nn * 16 + lo;
        int cc = ((ks * 4 + hi) ^ (lo & 7)) * 8;
        bfr[nn] = *(const s16x8*)&Bs[buf][row * 64 + cc];
      }
      #pragma unroll
      for (int m = 0; m < 2; ++m)
        #pragma unroll
        for (int nn = 0; nn < 4; ++nn)
          acc[m][nn] = __builtin_amdgcn_mfma_f32_16x16x32_bf16(af[m], bfr[nn], acc[m][nn], 0, 0, 0);
    }
    __syncthreads();
    buf ^= 1;
  }
  #undef STAGE_N

  #pragma unroll
  for (int m = 0; m < 2; ++m)
    #pragma unroll
    for (int nn = 0; nn < 4; ++nn) {
      int r0 = m0 + wv * 32 + m * 16 + hi * 4;
      int cc = n0 + nn * 16 + lo;
      #pragma unroll
      for (int j = 0; j < 4; ++j) {
        float val = acc[m][nn][j];
        if (F32OUT) ((float*)Cp)[(size_t)(r0 + j) * Nn + cc] = val;
        else        ((unsigned short*)Cp)[(size_t)(r0 + j) * Nn + cc] = f2bf(val);
      }
    }
}

// ---------------------------------------------------------------------------
// K5: RoPE apply for K only: qkvt cols 1024..2047 -> kd [b*H][n][64] bf16
// ---------------------------------------------------------------------------
__global__ __launch_bounds__(256) void k_rope(const unsigned short* __restrict__ qkv,
                                              const float2* __restrict__ tab,
                                              unsigned short* __restrict__ k) {
  int bs = blockIdx.x;
  int bb = bs / NN, s = bs % NN;
  int lane = threadIdx.x & 63, wv = threadIdx.x >> 6;
  #pragma unroll
  for (int g = 16 + wv; g < 32; g += 4) {
    int h = g & 15;
    float val = bf2f(qkv[(size_t)bs * QKVN + g * 64 + lane]);
    float partner = __shfl_xor(val, 1);
    float2 cs = tab[(size_t)bs * 32 + (lane >> 1)];
    float out;
    if ((lane & 1) == 0) out = val * cs.x - partner * cs.y;      // t1*cos - t2*sin
    else                 out = partner * cs.y + val * cs.x;      // t1*sin + t2*cos
    k[((size_t)(bb * HH + h) * NN + s) * 64 + lane] = f2bf(out);
  }
}

// ---------------------------------------------------------------------------
// K5b: V transpose + PV slot-permutation:
// qkvt[.][2048+h*64+dh] -> vT[bh][dh][64t + sigma(key%64)]
// sigma(k): bits [b5 b4 b3 b2 b1 b0] -> 32*b5 + 16*b3 + 8*b2 + 4*b4 + b1b0
// ---------------------------------------------------------------------------
__global__ __launch_bounds__(256) void k_vtr(const unsigned short* __restrict__ qkvt,
                                             unsigned short* __restrict__ vT) {
  __shared__ unsigned short t[64][72];
  int s0 = blockIdx.x * 64, bh = blockIdx.y, bb = bh >> 4, h = bh & 15;
  int tid = threadIdx.x;
  int r = tid >> 2, c0 = (tid & 3) * 16;
  int cw = c0 ^ (((r >> 4) & 3) << 4);
  const unsigned short* src = qkvt + (size_t)(bb * NN + s0 + r) * QKVN + 2048 + h * 64 + c0;
  *(s16x8*)&t[r][cw]     = *(const s16x8*)src;
  *(s16x8*)&t[r][cw + 8] = *(const s16x8*)(src + 8);
  __syncthreads();
  int dh = tid >> 2, sc = (tid & 3) * 16;
  int col2 = dh ^ ((tid & 3) << 4);
  s16x8 o1, o2;
  #pragma unroll
  for (int i = 0; i < 8; ++i) {
    o1[i] = (short)t[sc + i][col2];
    o2[i] = (short)t[sc + 8 + i][col2];
  }
  unsigned short* dst = vT + ((size_t)bh * 64 + dh) * NN + s0;
  int pb = (sc & 32) + (((sc >> 4) & 1) << 2);
  s16x4 g0 = __builtin_shufflevector(o1, o1, 0, 1, 2, 3);
  s16x4 g1 = __builtin_shufflevector(o1, o1, 4, 5, 6, 7);
  s16x4 g2 = __builtin_shufflevector(o2, o2, 0, 1, 2, 3);
  s16x4 g3 = __builtin_shufflevector(o2, o2, 4, 5, 6, 7);
  *(s16x4*)&dst[pb]      = g0;
  *(s16x4*)&dst[pb + 8]  = g1;
  *(s16x4*)&dst[pb + 16] = g2;
  *(s16x4*)&dst[pb + 24] = g3;
}

// ---------------------------------------------------------------------------
// K6: flash attention, KVBLK=128 dbuf (R14 shell), 8 waves repartitioned as
// (tile, rowgroup, kv-half): each wave = 32 q-rows x 64-key half, sharing
// K/V fragment reads across 2 q-fragments (halves LDS read traffic).
// End: partner kv-half waves combine accO/lr via reused LDS scratch.
// In-register Q-RoPE, swapped QK^T, cvt_pk P, sigma-permuted vT.
// ---------------------------------------------------------------------------
__global__ __launch_bounds__(512, 4) void k_attn(const unsigned short* __restrict__ qkvt,
                                                 const float2* __restrict__ tab,
                                                 const unsigned short* __restrict__ k,
                                                 const unsigned short* __restrict__ vT,
                                                 const int* __restrict__ mods,
                                                 unsigned short* __restrict__ o) {
  __shared__ unsigned short Ks[2][128 * 64];   // 128 keys x 64 dh (32 KB)
  __shared__ unsigned short Vs[2][64 * 128];   // 64 dh x 128 keys (32 KB)
  int tid = threadIdx.x;
  int lane = tid & 63, wv = tid >> 6;
  int lo = lane & 15, hi = lane >> 4;
  int t_ = wv >> 2;          // 0 = long tile, 1 = short tile
  int rg = (wv >> 1) & 1;    // row group (32 rows)
  int hf = wv & 1;           // kv half

  int fid = blockIdx.y * gridDim.x + blockIdx.x;      // 0..511
  int nid = (fid & 7) * 64 + (fid >> 3);              // XCD-contiguous
  int bh = nid >> 4;
  int bx = nid & 15;
  int bb = bh >> 4;
  int h = bh & 15;
  int q0A = (31 - bx) * 64;                           // long tile
  int q0B = bx * 64;                                  // mirror short tile
  int q0w = (t_ ? q0B : q0A) + rg * 32;               // 32 rows per wave

  const unsigned short* kb = k + (size_t)bh * NN * 64;
  const unsigned short* vb = vT + (size_t)bh * 64 * NN;

  // Q fragments (2 x 16 rows), raw GEMM output + in-register RoPE.
  s16x8 qf[2][2];
  #pragma unroll
  for (int fr = 0; fr < 2; ++fr) {
    int qrow = q0w + fr * 16 + lo;
    const unsigned short* qp = qkvt + (size_t)(bb * NN + qrow) * QKVN + h * 64;
    const float2* tb = tab + (size_t)(bb * NN + qrow) * 32;
    #pragma unroll
    for (int ks = 0; ks < 2; ++ks) {
      s16x8 raw = *(const s16x8*)&qp[ks * 32 + hi * 8];
      #pragma unroll
      for (int e2 = 0; e2 < 4; ++e2) {
        float2 cs = tb[ks * 16 + hi * 4 + e2];
        float t1 = bf2f((unsigned short)raw[2 * e2]);
        float t2 = bf2f((unsigned short)raw[2 * e2 + 1]);
        float o1 = (t1 * cs.x - t2 * cs.y) * 0.18033688011112042f; // 0.125*log2e
        float o2 = (t1 * cs.y + t2 * cs.x) * 0.18033688011112042f;
        qf[fr][ks][2 * e2]     = (short)f2bf(o1);
        qf[fr][ks][2 * e2 + 1] = (short)f2bf(o2);
      }
    }
  }

  int off_[MMOD], end_[MMOD];
  #pragma unroll
  for (int m = 0; m < MMOD; ++m) {
    off_[m] = mods[(bb * MMOD + m) * 3 + 1];
    end_[m] = off_[m] + mods[(bb * MMOD + m) * 3 + 2];
  }
  int limit_lf[2];
  #pragma unroll
  for (int fr = 0; fr < 2; ++fr) {
    int r = q0w + fr * 16 + lo;
    int L = r + 1;
    #pragma unroll
    for (int m = 0; m < MMOD; ++m)
      if (off_[m] <= r && end_[m] > L) L = end_[m];
    limit_lf[fr] = L;
  }
  int minlim, kvmax_w;
  {
    int L = q0w + 1;
    #pragma unroll
    for (int m = 0; m < MMOD; ++m)
      if (off_[m] <= q0w && end_[m] > L) L = end_[m];
    minlim = L;
    int r = q0w + 31;
    int L2 = r + 1;
    #pragma unroll
    for (int m = 0; m < MMOD; ++m)
      if (off_[m] <= r && end_[m] > L2) L2 = end_[m];
    kvmax_w = L2;
  }
  int nt;
  {
    int ra = q0A + 63;
    int LA = ra + 1;
    #pragma unroll
    for (int m = 0; m < MMOD; ++m)
      if (off_[m] <= ra && end_[m] > LA) LA = end_[m];
    int rb2 = q0B + 63;
    int LB = rb2 + 1;
    #pragma unroll
    for (int m = 0; m < MMOD; ++m)
      if (off_[m] <= rb2 && end_[m] > LB) LB = end_[m];
    int Lblk = (LA > LB) ? LA : LB;
    nt = (Lblk + 127) >> 7;
  }

  // Stage 128-key K/V tile (identical to R14): 2 shots x 512 thr x 16B each.
  #define STAGE_KV(B, KV0) do { \
    _Pragma("unroll") \
    for (int i_ = 0; i_ < 2; ++i_) { \
      int rK_ = i_ * 64 + (tid >> 3); \
      int csK_ = (lane & 7) ^ ((tid >> 3) & 7); \
      const unsigned short* gK_ = kb + (size_t)((KV0) + rK_) * 64 + csK_ * 8; \
      ASYNC_LDS16(gK_, &Ks[B][(i_ * 512 + wv * 64) * 8]); \
      int dhV_ = i_ * 32 + wv * 4 + (lane >> 4); \
      int ccV_ = ((lane & 7) ^ (dhV_ & 7)) | (lane & 8); \
      const unsigned short* gV_ = vb + (size_t)dhV_ * NN + (KV0) + ccV_ * 8; \
      ASYNC_LDS16(gV_, &Vs[B][(i_ * 512 + wv * 64) * 8]); \
    } \
  } while (0)

  float lrf[2] = {0.f, 0.f};
  f32x4 accO[2][4] = {};

  STAGE_KV(0, 0);
  __syncthreads();
  int buf = 0;
  for (int t = 0; t < nt; ++t) {
    if (t + 1 < nt) STAGE_KV(buf ^ 1, (t + 1) << 7);
    int kv0h = (t << 7) + hf * 64;
    if (kv0h < kvmax_w) {
      // S^T for both fragments; K fragments read ONCE, fed to 2 q-frags.
      f32x4 sv[2][4];
      __builtin_amdgcn_s_setprio(1);
      #pragma unroll
      for (int cb = 0; cb < 4; ++cb) {
        int krow = hf * 64 + cb * 16 + lo;
        int c0 = (hi) ^ (krow & 7);
        int c1 = (4 + hi) ^ (krow & 7);
        s16x8 kf0 = *(const s16x8*)&Ks[buf][krow * 64 + c0 * 8];
        s16x8 kf1 = *(const s16x8*)&Ks[buf][krow * 64 + c1 * 8];
        #pragma unroll
        for (int fr = 0; fr < 2; ++fr) {
          f32x4 z = {};
          z = __builtin_amdgcn_mfma_f32_16x16x32_bf16(kf0, qf[fr][0], z, 0, 0, 0);
          z = __builtin_amdgcn_mfma_f32_16x16x32_bf16(kf1, qf[fr][1], z, 0, 0, 0);
          sv[fr][cb] = z;
        }
      }
      __builtin_amdgcn_s_setprio(0);

      // p = exp2(s - s^3*k2); e^-50 shift cancels in normalization
      unsigned int pk_[2][4][2];
      bool edge = (kv0h + 64 > minlim);
      int kb0 = kv0h + hi * 4;
      #pragma unroll
      for (int fr = 0; fr < 2; ++fr)
        #pragma unroll
        for (int cb = 0; cb < 4; ++cb) {
          float p[4];
          #pragma unroll
          for (int j = 0; j < 4; ++j) {
            float s = sv[fr][cb][j];
            float u = __builtin_fmaf(s * s, -6.40604e-5f, 1.0f);
            float pp = __builtin_amdgcn_exp2f(s * u);
            if (edge && (kb0 + cb * 16 + j) >= limit_lf[fr]) pp = 0.f;
            p[j] = pp;
          }
          lrf[fr] += (p[0] + p[1]) + (p[2] + p[3]);
          pk_[fr][cb][0] = cvt_pk_bf16(p[0], p[1]);
          pk_[fr][cb][1] = cvt_pk_bf16(p[2], p[3]);
        }

      // pa per fragment, sigma slot order; V fragments read ONCE for 2 frags.
      union { unsigned int u[4]; s16x8 v; } pa[2][2];
      #pragma unroll
      for (int fr = 0; fr < 2; ++fr)
        #pragma unroll
        for (int ks2 = 0; ks2 < 2; ++ks2) {
          pa[fr][ks2].u[0] = pk_[fr][2 * ks2][0];
          pa[fr][ks2].u[1] = pk_[fr][2 * ks2][1];
          pa[fr][ks2].u[2] = pk_[fr][2 * ks2 + 1][0];
          pa[fr][ks2].u[3] = pk_[fr][2 * ks2 + 1][1];
        }

      __builtin_amdgcn_s_setprio(1);
      #pragma unroll
      for (int ks2 = 0; ks2 < 2; ++ks2) {
        #pragma unroll
        for (int cbo = 0; cbo < 4; ++cbo) {
          int vrow = cbo * 16 + lo;
          int vc = ((hf * 2 + ks2) * 4 + hi) ^ (vrow & 7);
          s16x8 vf = *(const s16x8*)&Vs[buf][vrow * 128 + vc * 8];
          accO[0][cbo] = __builtin_amdgcn_mfma_f32_16x16x32_bf16(pa[0][ks2].v, vf, accO[0][cbo], 0, 0, 0);
          accO[1][cbo] = __builtin_amdgcn_mfma_f32_16x16x32_bf16(pa[1][ks2].v, vf, accO[1][cbo], 0, 0, 0);
        }
      }
      __builtin_amdgcn_s_setprio(0);
    }
    __syncthreads();
    buf ^= 1;
  }

  // lr: reduce over hi groups -> per-lane row total for this kv-half
  #pragma unroll
  for (int fr = 0; fr < 2; ++fr) {
    lrf[fr] += __shfl_xor(lrf[fr], 16);
    lrf[fr] += __shfl_xor(lrf[fr], 32);
  }

  // cross-half combine via reused LDS (Ks: accO scratch 32KB; Vs: lr)
  float* accbuf = (float*)&Ks[0][0];
  float* lrbuf  = (float*)&Vs[0][0];
  if (lane < 16) {
    lrbuf[wv * 32 + lo]      = lrf[0];
    lrbuf[wv * 32 + 16 + lo] = lrf[1];
  }
  if (hf == 1) {
    float* ab = accbuf + ((size_t)(wv >> 1) * 64 + lane) * 32;
    #pragma unroll
    for (int fr = 0; fr < 2; ++fr)
      #pragma unroll
      for (int cbo = 0; cbo < 4; ++cbo)
        #pragma unroll
        for (int j = 0; j < 4; ++j)
          ab[fr * 16 + cbo * 4 + j] = accO[fr][cbo][j];
  }
  __syncthreads();
  if (hf == 0) {
    const float* ab = accbuf + ((size_t)(wv >> 1) * 64 + lane) * 32;
    #pragma unroll
    for (int fr = 0; fr < 2; ++fr) {
      #pragma unroll
      for (int j = 0; j < 4; ++j) {
        int row32 = fr * 16 + hi * 4 + j;
        float lt = lrbuf[wv * 32 + row32] + lrbuf[(wv + 1) * 32 + row32];
        float rl = __builtin_amdgcn_rcpf(lt);
        int rout = q0w + row32;
        size_t base = ((size_t)(bb * NN) + rout) * (HH * DHD) + h * 64;
        #pragma unroll
        for (int cbo = 0; cbo < 4; ++cbo) {
          float val = (accO[fr][cbo][j] + ab[fr * 16 + cbo * 4 + j]) * rl;
          o[base + cbo * 16 + lo] = f2bf(val);
        }
      }
    }
  }
}

// ---------------------------------------------------------------------------
extern "C" void kernel_launch(void* const* d_in, const int* in_sizes, int n_in,
                              void* d_out, int out_size, void* d_ws, size_t ws_size,
                              hipStream_t stream) {
  (void)in_sizes; (void)n_in; (void)out_size; (void)ws_size;
  const float* x      = (const float*)d_in[0];
  const float* tokens = (const float*)d_in[1];
  const float* gamma  = (const float*)d_in[2];
  const float* w_qkv  = (const float*)d_in[3];
  const float* w_out  = (const float*)d_in[4];
  const int*   mods   = (const int*)d_in[5];

  char* ws = (char*)d_ws;
  unsigned short* xn    = (unsigned short*)(ws + 0);           //  8 MB
  unsigned short* wqkvT = (unsigned short*)(ws + 8388608);     //  6 MB
  unsigned short* woutT = (unsigned short*)(ws + 14680064);    //  2 MB
  unsigned short* qkvt  = (unsigned short*)(ws + 16777216);    // 24 MB
  unsigned short* kd    = (unsigned short*)(ws + 50331648);    //  8 MB
  unsigned short* vTd   = (unsigned short*)(ws + 58720256);    //  8 MB
  unsigned short* attno = (unsigned short*)(ws + 67108864);    //  8 MB
  int*            pos   = (int*)(ws + 75497472);               // 16 KB
  float2*         tab   = (float2*)(ws + 75513856);            //  1 MB

  k_prep<<<BNROWS, 256, 0, stream>>>(x, tokens, gamma, mods, xn);
  k_pos<<<BB, 64, 0, stream>>>(mods, pos);
  k_tab<<<(BB * NN * 32) / 256, 256, 0, stream>>>(pos, tab);
  k_tr<<<dim3(QKVN / 32, DD / 32), dim3(32, 8), 0, stream>>>(w_qkv, wqkvT, DD, QKVN);
  k_tr<<<dim3((HH * DHD) / 32, DD / 32), dim3(32, 8), 0, stream>>>(w_out, woutT, HH * DHD, DD);
  k_gemm<false><<<dim3(QKVN / 128, BNROWS / 128), 256, 0, stream>>>(xn, wqkvT, (void*)qkvt, BNROWS, QKVN, DD);
  k_rope<<<BNROWS, 256, 0, stream>>>(qkvt, tab, kd);
  k_vtr<<<dim3(NN / 64, BB * HH), 256, 0, stream>>>(qkvt, vTd);
  k_attn<<<dim3(16, BB * HH), 512, 0, stream>>>(qkvt, tab, kd, vTd, mods, attno);
  k_gemm_n64<true><<<dim3(DD / 64, BNROWS / 128), 256, 0, stream>>>(attno, woutT, (void*)d_out, BNROWS, DD, HH * DHD);
}

// Round 17
// 141.081 us; speedup vs baseline: 1.0836x; 1.0091x over previous
//
#include <hip/hip_runtime.h>
#include <stdint.h>

#define HH 16
#define DHD 64
#define BB 2
#define NN 2048
#define DD 1024
#define MMOD 4
#define LMAX 256
#define BNROWS (BB*NN)      // 4096
#define QKVN (3*HH*DHD)     // 3072

typedef __attribute__((ext_vector_type(4))) float f32x4;
typedef __attribute__((ext_vector_type(8))) short s16x8;
typedef __attribute__((ext_vector_type(4))) short s16x4;

__device__ __forceinline__ float bf2f(unsigned short b) {
  return __uint_as_float(((unsigned int)b) << 16);
}
__device__ __forceinline__ unsigned short f2bf(float f) {
  unsigned int u = __float_as_uint(f);
  u += 0x7fffu + ((u >> 16) & 1u);
  return (unsigned short)(u >> 16);
}
__device__ __forceinline__ unsigned int cvt_pk_bf16(float a, float b) {
  unsigned int r;
  asm("v_cvt_pk_bf16_f32 %0, %1, %2" : "=v"(r) : "v"(a), "v"(b));
  return r;
}

#define ASYNC_LDS16(g, l) \
  __builtin_amdgcn_global_load_lds((const __attribute__((address_space(1))) void*)(g), \
                                   (__attribute__((address_space(3))) void*)(l), 16, 0, 0)

// ---------------------------------------------------------------------------
// K1: modality splice + norm + gamma, write xn bf16 [4096][1024]
// ---------------------------------------------------------------------------
__global__ __launch_bounds__(256) void k_prep(const float* __restrict__ x,
                                              const float* __restrict__ tokens,
                                              const float* __restrict__ gamma,
                                              const int* __restrict__ mods,
                                              unsigned short* __restrict__ xn) {
  int bs = blockIdx.x;
  int bb = bs / NN, s = bs % NN;
  int t = threadIdx.x;
  int c = t * 4;
  const float4 xv = *(const float4*)(x + (size_t)bs * DD + c);
  float4 acc = {0.f, 0.f, 0.f, 0.f};
  bool any = false;
  #pragma unroll
  for (int m = 0; m < MMOD; ++m) {
    int off = mods[(bb * MMOD + m) * 3 + 1];
    int ln  = mods[(bb * MMOD + m) * 3 + 2];
    if (s >= off && s < off + ln) {
      any = true;
      int rel = s - off;
      if (rel > LMAX - 1) rel = LMAX - 1;
      if (rel < 0) rel = 0;
      const float4 tv = *(const float4*)(tokens + ((size_t)(bb * MMOD + m) * LMAX + rel) * DD + c);
      acc.x += tv.x; acc.y += tv.y; acc.z += tv.z; acc.w += tv.w;
    }
  }
  float4 v = any ? acc : xv;
  float ss = v.x*v.x + v.y*v.y + v.z*v.z + v.w*v.w;
  #pragma unroll
  for (int o = 32; o; o >>= 1) ss += __shfl_xor(ss, o);
  __shared__ float red[4];
  int wv = t >> 6;
  if ((t & 63) == 0) red[wv] = ss;
  __syncthreads();
  float tot = red[0] + red[1] + red[2] + red[3];
  float norm = sqrtf(tot);
  norm = fmaxf(norm, 1e-12f);
  float sc = 32.0f / norm;   // sqrt(1024) = 32
  const float4 g = *(const float4*)(gamma + c);
  unsigned long long pk =
      (unsigned long long)f2bf(v.x * sc * (g.x + 1.f)) |
      ((unsigned long long)f2bf(v.y * sc * (g.y + 1.f)) << 16) |
      ((unsigned long long)f2bf(v.z * sc * (g.z + 1.f)) << 32) |
      ((unsigned long long)f2bf(v.w * sc * (g.w + 1.f)) << 48);
  *(unsigned long long*)(xn + (size_t)bs * DD + c) = pk;
}

// ---------------------------------------------------------------------------
// K2: pos[b][n] = s - cumsum(rot_any). One wave per batch.
// ---------------------------------------------------------------------------
__global__ void k_pos(const int* __restrict__ mods, int* __restrict__ pos) {
  int bb = blockIdx.x;
  int lane = threadIdx.x;       // 64
  int offs[MMOD], ends[MMOD];
  #pragma unroll
  for (int m = 0; m < MMOD; ++m) {
    int off = mods[(bb * MMOD + m) * 3 + 1];
    int ln  = mods[(bb * MMOD + m) * 3 + 2];
    offs[m] = off + 1;
    ends[m] = off + ln;
  }
  int base = lane * (NN / 64);  // 32 per lane
  int lc[NN / 64];
  int tot = 0;
  #pragma unroll
  for (int i = 0; i < NN / 64; ++i) {
    int s = base + i;
    int f = 0;
    #pragma unroll
    for (int m = 0; m < MMOD; ++m)
      if (s >= offs[m] && s < ends[m]) f = 1;
    tot += f;
    lc[i] = tot;
  }
  int v = tot;
  #pragma unroll
  for (int o = 1; o < 64; o <<= 1) {
    int u = __shfl_up(v, o);
    if (lane >= o) v += u;
  }
  int excl = v - tot;
  #pragma unroll
  for (int i = 0; i < NN / 64; ++i)
    pos[bb * NN + base + i] = base + i - (excl + lc[i]);
}

// ---------------------------------------------------------------------------
// K2b: RoPE cos/sin table [b*n][32] float2
// ---------------------------------------------------------------------------
__global__ void k_tab(const int* __restrict__ pos, float2* __restrict__ tab) {
  int gid = blockIdx.x * 256 + threadIdx.x;   // b*n*32 = 131072
  int p = gid & 31;
  int bs = gid >> 5;
  float inv = expf(-((float)p / 32.f) * 9.210340371976184f); // 1/10000^(2p/64)
  float ang = (float)pos[bs] * inv;
  float sn, cs;
  sincosf(ang, &sn, &cs);
  tab[gid] = make_float2(cs, sn);
}

// ---------------------------------------------------------------------------
// K3: merged weight transposes: f32 [R][C] -> bf16 [C][R] for both weights
// blocks 0..3071: w_qkv (96x32 tile grid); 3072..4095: w_out (32x32)
// ---------------------------------------------------------------------------
__global__ void k_tr2(const float* __restrict__ w_qkv, const float* __restrict__ w_out,
                      unsigned short* __restrict__ wqkvT, unsigned short* __restrict__ woutT) {
  __shared__ float tile[32][33];
  int bid = blockIdx.x;
  const float* in;
  unsigned short* out;
  int R, C, bx, by;
  if (bid < 3072) {
    in = w_qkv; out = wqkvT; R = DD; C = QKVN;
    bx = bid % 96; by = bid / 96;
  } else {
    int b2 = bid - 3072;
    in = w_out; out = woutT; R = HH * DHD; C = DD;
    bx = b2 % 32; by = b2 / 32;
  }
  int tx = threadIdx.x, ty = threadIdx.y;
  #pragma unroll
  for (int k = 0; k < 4; ++k) {
    int r = by * 32 + ty + k * 8, c = bx * 32 + tx;
    tile[ty + k * 8][tx] = in[(size_t)r * C + c];
  }
  __syncthreads();
  #pragma unroll
  for (int k = 0; k < 4; ++k) {
    int oc = bx * 32 + ty + k * 8;
    int orr = by * 32 + tx;
    out[(size_t)oc * R + orr] = f2bf(tile[tx][ty + k * 8]);
  }
}

// ---------------------------------------------------------------------------
// K4: QKV GEMM 128x128, BK=64, 4 waves, dbuf LDS + XOR swz + XCD swizzle.
// ---------------------------------------------------------------------------
template<bool F32OUT>
__global__ __launch_bounds__(256) void k_gemm(const unsigned short* __restrict__ A,
                                              const unsigned short* __restrict__ Bt,
                                              void* __restrict__ Cp,
                                              int M, int Nn, int K) {
  __shared__ unsigned short As[2][128 * 64];
  __shared__ unsigned short Bs[2][128 * 64];
  int tid = threadIdx.x;
  int lane = tid & 63, wv = tid >> 6;
  int lo = lane & 15, hi = lane >> 4;
  int nb = gridDim.x * gridDim.y;
  int fid = blockIdx.y * gridDim.x + blockIdx.x;
  int cpx = nb >> 3;
  int nid = (fid & 7) * cpx + (fid >> 3);      // contiguous chunk per XCD
  int m0 = (nid / gridDim.x) * 128;
  int n0 = (nid % gridDim.x) * 128;
  int wr = wv >> 1, wc = wv & 1;
  f32x4 acc[4][4] = {};

  int srow = tid >> 3;
  int scs  = ((tid & 7) ^ ((tid >> 3) & 7)) * 8;
  #define STAGE_G(BUF, KT) do { \
    _Pragma("unroll") \
    for (int is_ = 0; is_ < 4; ++is_) { \
      int r_ = is_ * 32 + srow; \
      const unsigned short* ga_ = A  + (size_t)(m0 + r_) * K + (KT) + scs; \
      const unsigned short* gb_ = Bt + (size_t)(n0 + r_) * K + (KT) + scs; \
      ASYNC_LDS16(ga_, &As[BUF][(is_ * 256 + wv * 64) * 8]); \
      ASYNC_LDS16(gb_, &Bs[BUF][(is_ * 256 + wv * 64) * 8]); \
    } \
  } while (0)

  int nt = K >> 6;
  STAGE_G(0, 0);
  __syncthreads();
  int buf = 0;
  for (int t = 0; t < nt; ++t) {
    if (t + 1 < nt) STAGE_G(buf ^ 1, (t + 1) << 6);
    #pragma unroll
    for (int ks = 0; ks < 2; ++ks) {
      s16x8 af[4], bfr[4];
      #pragma unroll
      for (int m = 0; m < 4; ++m) {
        int row = wr * 64 + m * 16 + lo;
        int cc = ((ks * 4 + hi) ^ (lo & 7)) * 8;
        af[m] = *(const s16x8*)&As[buf][row * 64 + cc];
      }
      #pragma unroll
      for (int nn = 0; nn < 4; ++nn) {
        int row = wc * 64 + nn * 16 + lo;
        int cc = ((ks * 4 + hi) ^ (lo & 7)) * 8;
        bfr[nn] = *(const s16x8*)&Bs[buf][row * 64 + cc];
      }
      #pragma unroll
      for (int m = 0; m < 4; ++m)
        #pragma unroll
        for (int nn = 0; nn < 4; ++nn)
          acc[m][nn] = __builtin_amdgcn_mfma_f32_16x16x32_bf16(af[m], bfr[nn], acc[m][nn], 0, 0, 0);
    }
    __syncthreads();
    buf ^= 1;
  }
  #undef STAGE_G

  #pragma unroll
  for (int m = 0; m < 4; ++m) {
    #pragma unroll
    for (int nn = 0; nn < 4; ++nn) {
      int r0 = m0 + wr * 64 + m * 16 + hi * 4;
      int cc = n0 + wc * 64 + nn * 16 + lo;
      #pragma unroll
      for (int j = 0; j < 4; ++j) {
        float val = acc[m][nn][j];
        if (F32OUT) ((float*)Cp)[(size_t)(r0 + j) * Nn + cc] = val;
        else        ((unsigned short*)Cp)[(size_t)(r0 + j) * Nn + cc] = f2bf(val);
      }
    }
  }
}

// ---------------------------------------------------------------------------
// K7: out-proj GEMM, BM=128 BN=64 (grid 512), 4 waves stacked, acc[2][4].
// ---------------------------------------------------------------------------
template<bool F32OUT>
__global__ __launch_bounds__(256) void k_gemm_n64(const unsigned short* __restrict__ A,
                                                  const unsigned short* __restrict__ Bt,
                                                  void* __restrict__ Cp,
                                                  int M, int Nn, int K) {
  __shared__ unsigned short As[2][128 * 64];
  __shared__ unsigned short Bs[2][64 * 64];
  int tid = threadIdx.x;
  int lane = tid & 63, wv = tid >> 6;
  int lo = lane & 15, hi = lane >> 4;
  int nb = gridDim.x * gridDim.y;
  int fid = blockIdx.y * gridDim.x + blockIdx.x;
  int cpx = nb >> 3;
  int nid = (fid & 7) * cpx + (fid >> 3);
  int m0 = (nid / gridDim.x) * 128;
  int n0 = (nid % gridDim.x) * 64;
  f32x4 acc[2][4] = {};

  int srow = tid >> 3;
  int scs  = ((tid & 7) ^ ((tid >> 3) & 7)) * 8;
  #define STAGE_N(BUF, KT) do { \
    _Pragma("unroll") \
    for (int is_ = 0; is_ < 4; ++is_) { \
      int r_ = is_ * 32 + srow; \
      const unsigned short* ga_ = A + (size_t)(m0 + r_) * K + (KT) + scs; \
      ASYNC_LDS16(ga_, &As[BUF][(is_ * 256 + wv * 64) * 8]); \
    } \
    _Pragma("unroll") \
    for (int is_ = 0; is_ < 2; ++is_) { \
      int r_ = is_ * 32 + srow; \
      const unsigned short* gb_ = Bt + (size_t)(n0 + r_) * K + (KT) + scs; \
      ASYNC_LDS16(gb_, &Bs[BUF][(is_ * 256 + wv * 64) * 8]); \
    } \
  } while (0)

  int nt = K >> 6;
  STAGE_N(0, 0);
  __syncthreads();
  int buf = 0;
  for (int t = 0; t < nt; ++t) {
    if (t + 1 < nt) STAGE_N(buf ^ 1, (t + 1) << 6);
    #pragma unroll
    for (int ks = 0; ks < 2; ++ks) {
      s16x8 af[2], bfr[4];
      #pragma unroll
      for (int m = 0; m < 2; ++m) {
        int row = wv * 32 + m * 16 + lo;
        int cc = ((ks * 4 + hi) ^ (lo & 7)) * 8;
        af[m] = *(const s16x8*)&As[buf][row * 64 + cc];
      }
      #pragma unroll
      for (int nn = 0; nn < 4; ++nn) {
        int row = nn * 16 + lo;
        int cc = ((ks * 4 + hi) ^ (lo & 7)) * 8;
        bfr[nn] = *(const s16x8*)&Bs[buf][row * 64 + cc];
      }
      #pragma unroll
      for (int m = 0; m < 2; ++m)
        #pragma unroll
        for (int nn = 0; nn < 4; ++nn)
          acc[m][nn] = __builtin_amdgcn_mfma_f32_16x16x32_bf16(af[m], bfr[nn], acc[m][nn], 0, 0, 0);
    }
    __syncthreads();
    buf ^= 1;
  }
  #undef STAGE_N

  #pragma unroll
  for (int m = 0; m < 2; ++m)
    #pragma unroll
    for (int nn = 0; nn < 4; ++nn) {
      int r0 = m0 + wv * 32 + m * 16 + hi * 4;
      int cc = n0 + nn * 16 + lo;
      #pragma unroll
      for (int j = 0; j < 4; ++j) {
        float val = acc[m][nn][j];
        if (F32OUT) ((float*)Cp)[(size_t)(r0 + j) * Nn + cc] = val;
        else        ((unsigned short*)Cp)[(size_t)(r0 + j) * Nn + cc] = f2bf(val);
      }
    }
}

// ---------------------------------------------------------------------------
// K5: merged K-RoPE + V transpose.
// blocks 0..4095: RoPE K (qkvt cols 1024..2047 -> kd)
// blocks 4096..5119: V -> sigma-permuted vT
// sigma(k): bits [b5 b4 b3 b2 b1 b0] -> 32*b5 + 16*b3 + 8*b2 + 4*b4 + b1b0
// ---------------------------------------------------------------------------
__global__ __launch_bounds__(256) void k_ropevtr(const unsigned short* __restrict__ qkvt,
                                                 const float2* __restrict__ tab,
                                                 unsigned short* __restrict__ kd,
                                                 unsigned short* __restrict__ vT) {
  __shared__ unsigned short t[64][72];
  int bid = blockIdx.x;
  if (bid < BNROWS) {
    int bs = bid;
    int bb = bs / NN, s = bs % NN;
    int lane = threadIdx.x & 63, wv = threadIdx.x >> 6;
    #pragma unroll
    for (int g = 16 + wv; g < 32; g += 4) {
      int h = g & 15;
      float val = bf2f(qkvt[(size_t)bs * QKVN + g * 64 + lane]);
      float partner = __shfl_xor(val, 1);
      float2 cs = tab[(size_t)bs * 32 + (lane >> 1)];
      float out;
      if ((lane & 1) == 0) out = val * cs.x - partner * cs.y;    // t1*cos - t2*sin
      else                 out = partner * cs.y + val * cs.x;    // t1*sin + t2*cos
      kd[((size_t)(bb * HH + h) * NN + s) * 64 + lane] = f2bf(out);
    }
  } else {
    int idx = bid - BNROWS;
    int s0 = (idx & 31) * 64, bh = idx >> 5, bb = bh >> 4, h = bh & 15;
    int tid = threadIdx.x;
    int r = tid >> 2, c0 = (tid & 3) * 16;
    int cw = c0 ^ (((r >> 4) & 3) << 4);
    const unsigned short* src = qkvt + (size_t)(bb * NN + s0 + r) * QKVN + 2048 + h * 64 + c0;
    *(s16x8*)&t[r][cw]     = *(const s16x8*)src;
    *(s16x8*)&t[r][cw + 8] = *(const s16x8*)(src + 8);
    __syncthreads();
    int dh = tid >> 2, sc = (tid & 3) * 16;
    int col2 = dh ^ ((tid & 3) << 4);
    s16x8 o1, o2;
    #pragma unroll
    for (int i = 0; i < 8; ++i) {
      o1[i] = (short)t[sc + i][col2];
      o2[i] = (short)t[sc + 8 + i][col2];
    }
    unsigned short* dst = vT + ((size_t)bh * 64 + dh) * NN + s0;
    int pb = (sc & 32) + (((sc >> 4) & 1) << 2);
    s16x4 g0 = __builtin_shufflevector(o1, o1, 0, 1, 2, 3);
    s16x4 g1 = __builtin_shufflevector(o1, o1, 4, 5, 6, 7);
    s16x4 g2 = __builtin_shufflevector(o2, o2, 0, 1, 2, 3);
    s16x4 g3 = __builtin_shufflevector(o2, o2, 4, 5, 6, 7);
    *(s16x4*)&dst[pb]      = g0;
    *(s16x4*)&dst[pb + 8]  = g1;
    *(s16x4*)&dst[pb + 16] = g2;
    *(s16x4*)&dst[pb + 24] = g3;
  }
}

// ---------------------------------------------------------------------------
// K6: flash attention (R14 config) + in-register Q-RoPE. KVBLK=128,
// 8 waves, paired long/short q-tiles, dbuf K/V staging, swapped QK^T,
// cvt_pk P, PV b128 from XOR-swizzled sigma-permuted vT.
// Edge/interior softmax split (wave-uniform branch).
// ---------------------------------------------------------------------------
__global__ __launch_bounds__(512) void k_attn(const unsigned short* __restrict__ qkvt,
                                              const float2* __restrict__ tab,
                                              const unsigned short* __restrict__ k,
                                              const unsigned short* __restrict__ vT,
                                              const int* __restrict__ mods,
                                              unsigned short* __restrict__ o) {
  __shared__ unsigned short Ks[2][128 * 64];   // 128 keys x 64 dh
  __shared__ unsigned short Vs[2][64 * 128];   // 64 dh x 128 keys
  int tid = threadIdx.x;
  int lane = tid & 63, wv = tid >> 6;
  int lo = lane & 15, hi = lane >> 4;

  int fid = blockIdx.y * gridDim.x + blockIdx.x;      // 0..511
  int nid = (fid & 7) * 64 + (fid >> 3);              // XCD-contiguous (R12)
  int bh = nid >> 4;
  int bx = nid & 15;
  int bb = bh >> 4;
  int h = bh & 15;
  int q0A = (31 - bx) * 64;                           // long tile
  int q0B = bx * 64;                                  // mirror short tile
  int q0w = ((wv < 4) ? q0A : q0B) + (wv & 3) * 16;

  const unsigned short* kb = k + (size_t)bh * NN * 64;
  const unsigned short* vb = vT + (size_t)bh * 64 * NN;

  // Q fragments: raw GEMM output + in-register RoPE (pairs are adjacent).
  s16x8 qf[2];
  {
    int qrow = q0w + lo;
    const unsigned short* qp = qkvt + (size_t)(bb * NN + qrow) * QKVN + h * 64;
    const float2* tb = tab + (size_t)(bb * NN + qrow) * 32;
    #pragma unroll
    for (int ks = 0; ks < 2; ++ks) {
      s16x8 raw = *(const s16x8*)&qp[ks * 32 + hi * 8];
      #pragma unroll
      for (int e2 = 0; e2 < 4; ++e2) {
        float2 cs = tb[ks * 16 + hi * 4 + e2];
        float t1 = bf2f((unsigned short)raw[2 * e2]);
        float t2 = bf2f((unsigned short)raw[2 * e2 + 1]);
        float o1 = (t1 * cs.x - t2 * cs.y) * 0.18033688011112042f; // 0.125*log2e
        float o2 = (t1 * cs.y + t2 * cs.x) * 0.18033688011112042f;
        qf[ks][2 * e2]     = (short)f2bf(o1);
        qf[ks][2 * e2 + 1] = (short)f2bf(o2);
      }
    }
  }

  int off_[MMOD], end_[MMOD];
  #pragma unroll
  for (int m = 0; m < MMOD; ++m) {
    off_[m] = mods[(bb * MMOD + m) * 3 + 1];
    end_[m] = off_[m] + mods[(bb * MMOD + m) * 3 + 2];
  }
  int limit_l;
  {
    int r = q0w + lo;
    int L = r + 1;
    #pragma unroll
    for (int m = 0; m < MMOD; ++m)
      if (off_[m] <= r && end_[m] > L) L = end_[m];
    limit_l = L;
  }
  int minlim, kvmax_w;
  {
    int L = q0w + 1;
    #pragma unroll
    for (int m = 0; m < MMOD; ++m)
      if (off_[m] <= q0w && end_[m] > L) L = end_[m];
    minlim = L;
    int r = q0w + 15;
    int L2 = r + 1;
    #pragma unroll
    for (int m = 0; m < MMOD; ++m)
      if (off_[m] <= r && end_[m] > L2) L2 = end_[m];
    kvmax_w = L2;
  }
  int nt;
  {
    int ra = q0A + 63;
    int LA = ra + 1;
    #pragma unroll
    for (int m = 0; m < MMOD; ++m)
      if (off_[m] <= ra && end_[m] > LA) LA = end_[m];
    int rb2 = q0B + 63;
    int LB = rb2 + 1;
    #pragma unroll
    for (int m = 0; m < MMOD; ++m)
      if (off_[m] <= rb2 && end_[m] > LB) LB = end_[m];
    int Lblk = (LA > LB) ? LA : LB;
    nt = (Lblk + 127) >> 7;
  }

  // Stage 128-key K/V tile: 2 shots x 512 threads x 16B for each of K,V.
  #define STAGE_KV(B, KV0) do { \
    _Pragma("unroll") \
    for (int i_ = 0; i_ < 2; ++i_) { \
      int rK_ = i_ * 64 + (tid >> 3); \
      int csK_ = (lane & 7) ^ ((tid >> 3) & 7); \
      const unsigned short* gK_ = kb + (size_t)((KV0) + rK_) * 64 + csK_ * 8; \
      ASYNC_LDS16(gK_, &Ks[B][(i_ * 512 + wv * 64) * 8]); \
      int dhV_ = i_ * 32 + wv * 4 + (lane >> 4); \
      int ccV_ = ((lane & 7) ^ (dhV_ & 7)) | (lane & 8); \
      const unsigned short* gV_ = vb + (size_t)dhV_ * NN + (KV0) + ccV_ * 8; \
      ASYNC_LDS16(gV_, &Vs[B][(i_ * 512 + wv * 64) * 8]); \
    } \
  } while (0)

  float lr = 0.f;
  f32x4 accO[4] = {};

  STAGE_KV(0, 0);
  __syncthreads();
  int buf = 0;
  for (int t = 0; t < nt; ++t) {
    if (t + 1 < nt) STAGE_KV(buf ^ 1, (t + 1) << 7);
    int kv0 = t << 7;
    if (kv0 < kvmax_w) {
      // S^T = K Q^T; sv[cb][j] = S[qrow=lo][key=kv0+cb*16+hi*4+j], cb 0..7
      f32x4 sv[8];
      __builtin_amdgcn_s_setprio(1);
      #pragma unroll
      for (int cb = 0; cb < 8; ++cb) {
        int krow = cb * 16 + lo;
        int c0 = (hi) ^ (krow & 7);
        int c1 = (4 + hi) ^ (krow & 7);
        s16x8 kf0 = *(const s16x8*)&Ks[buf][krow * 64 + c0 * 8];
        s16x8 kf1 = *(const s16x8*)&Ks[buf][krow * 64 + c1 * 8];
        f32x4 z = {};
        z = __builtin_amdgcn_mfma_f32_16x16x32_bf16(kf0, qf[0], z, 0, 0, 0);
        z = __builtin_amdgcn_mfma_f32_16x16x32_bf16(kf1, qf[1], z, 0, 0, 0);
        sv[cb] = z;
      }
      __builtin_amdgcn_s_setprio(0);

      // p = exp2(sv - sv^3*k2)  (== exp(s - s^3/7500), e^-50 shift cancels)
      unsigned int pk_[8][2];
      if (kv0 + 128 <= minlim) {
        // interior: no masking
        #pragma unroll
        for (int cb = 0; cb < 8; ++cb) {
          float p[4];
          #pragma unroll
          for (int j = 0; j < 4; ++j) {
            float s = sv[cb][j];
            float u = __builtin_fmaf(s * s, -6.40604e-5f, 1.0f);
            p[j] = __builtin_amdgcn_exp2f(s * u);
          }
          lr += (p[0] + p[1]) + (p[2] + p[3]);
          pk_[cb][0] = cvt_pk_bf16(p[0], p[1]);
          pk_[cb][1] = cvt_pk_bf16(p[2], p[3]);
        }
      } else {
        int kb0 = kv0 + hi * 4;
        #pragma unroll
        for (int cb = 0; cb < 8; ++cb) {
          float p[4];
          #pragma unroll
          for (int j = 0; j < 4; ++j) {
            float s = sv[cb][j];
            float u = __builtin_fmaf(s * s, -6.40604e-5f, 1.0f);
            float pp = __builtin_amdgcn_exp2f(s * u);
            if ((kb0 + cb * 16 + j) >= limit_l) pp = 0.f;
            p[j] = pp;
          }
          lr += (p[0] + p[1]) + (p[2] + p[3]);
          pk_[cb][0] = cvt_pk_bf16(p[0], p[1]);
          pk_[cb][1] = cvt_pk_bf16(p[2], p[3]);
        }
      }

      // pa[ks'] covers keys of cb = ks'*2 .. ks'*2+1 groups (sigma order)
      union { unsigned int u[4]; s16x8 v; } pa[4];
      #pragma unroll
      for (int kk = 0; kk < 4; ++kk) {
        pa[kk].u[0] = pk_[2 * kk][0];
        pa[kk].u[1] = pk_[2 * kk][1];
        pa[kk].u[2] = pk_[2 * kk + 1][0];
        pa[kk].u[3] = pk_[2 * kk + 1][1];
      }

      // PV from swizzled LDS (row stride 128): conflict-free b128 reads
      __builtin_amdgcn_s_setprio(1);
      #pragma unroll
      for (int ks = 0; ks < 4; ++ks) {
        #pragma unroll
        for (int cbo = 0; cbo < 4; ++cbo) {
          int vrow = cbo * 16 + lo;
          int vc = (ks * 4 + hi) ^ (vrow & 7);
          s16x8 vf = *(const s16x8*)&Vs[buf][vrow * 128 + vc * 8];
          accO[cbo] = __builtin_amdgcn_mfma_f32_16x16x32_bf16(pa[ks].v, vf, accO[cbo], 0, 0, 0);
        }
      }
      __builtin_amdgcn_s_setprio(0);
    }
    __syncthreads();
    buf ^= 1;
  }

  // denominator: total for qrow=lo, redistribute to output rows hi*4+j
  lr += __shfl_xor(lr, 16);
  lr += __shfl_xor(lr, 32);
  float rl[4];
  #pragma unroll
  for (int j = 0; j < 4; ++j)
    rl[j] = __builtin_amdgcn_rcpf(__shfl(lr, hi * 4 + j));

  #pragma unroll
  for (int cb = 0; cb < 4; ++cb)
    #pragma unroll
    for (int j = 0; j < 4; ++j) {
      int r = q0w + hi * 4 + j;
      float val = accO[cb][j] * rl[j];
      o[((size_t)(bb * NN) + r) * (HH * DHD) + h * 64 + cb * 16 + lo] = f2bf(val);
    }
}

// ---------------------------------------------------------------------------
extern "C" void kernel_launch(void* const* d_in, const int* in_sizes, int n_in,
                              void* d_out, int out_size, void* d_ws, size_t ws_size,
                              hipStream_t stream) {
  (void)in_sizes; (void)n_in; (void)out_size; (void)ws_size;
  const float* x      = (const float*)d_in[0];
  const float* tokens = (const float*)d_in[1];
  const float* gamma  = (const float*)d_in[2];
  const float* w_qkv  = (const float*)d_in[3];
  const float* w_out  = (const float*)d_in[4];
  const int*   mods   = (const int*)d_in[5];

  char* ws = (char*)d_ws;
  unsigned short* xn    = (unsigned short*)(ws + 0);           //  8 MB
  unsigned short* wqkvT = (unsigned short*)(ws + 8388608);     //  6 MB
  unsigned short* woutT = (unsigned short*)(ws + 14680064);    //  2 MB
  unsigned short* qkvt  = (unsigned short*)(ws + 16777216);    // 24 MB
  unsigned short* kd    = (unsigned short*)(ws + 50331648);    //  8 MB
  unsigned short* vTd   = (unsigned short*)(ws + 58720256);    //  8 MB
  unsigned short* attno = (unsigned short*)(ws + 67108864);    //  8 MB
  int*            pos   = (int*)(ws + 75497472);               // 16 KB
  float2*         tab   = (float2*)(ws + 75513856);            //  1 MB

  k_prep<<<BNROWS, 256, 0, stream>>>(x, tokens, gamma, mods, xn);
  k_pos<<<BB, 64, 0, stream>>>(mods, pos);
  k_tab<<<(BB * NN * 32) / 256, 256, 0, stream>>>(pos, tab);
  k_tr2<<<4096, dim3(32, 8), 0, stream>>>(w_qkv, w_out, wqkvT, woutT);
  k_gemm<false><<<dim3(QKVN / 128, BNROWS / 128), 256, 0, stream>>>(xn, wqkvT, (void*)qkvt, BNROWS, QKVN, DD);
  k_ropevtr<<<BNROWS + 1024, 256, 0, stream>>>(qkvt, tab, kd, vTd);
  k_attn<<<dim3(16, BB * HH), 512, 0, stream>>>(qkvt, tab, kd, vTd, mods, attno);
  k_gemm_n64<true><<<dim3(DD / 64, BNROWS / 128), 256, 0, stream>>>(attno, woutT, (void*)d_out, BNROWS, DD, HH * DHD);
}

// Round 18
// 131.928 us; speedup vs baseline: 1.1588x; 1.0694x over previous
//
#include <hip/hip_runtime.h>
#include <stdint.h>

#define HH 16
#define DHD 64
#define BB 2
#define NN 2048
#define DD 1024
#define MMOD 4
#define LMAX 256
#define BNROWS (BB*NN)      // 4096
#define QKVN (3*HH*DHD)     // 3072

typedef __attribute__((ext_vector_type(4))) float f32x4;
typedef __attribute__((ext_vector_type(8))) short s16x8;
typedef __attribute__((ext_vector_type(4))) short s16x4;

__device__ __forceinline__ float bf2f(unsigned short b) {
  return __uint_as_float(((unsigned int)b) << 16);
}
__device__ __forceinline__ unsigned short f2bf(float f) {
  unsigned int u = __float_as_uint(f);
  u += 0x7fffu + ((u >> 16) & 1u);
  return (unsigned short)(u >> 16);
}
__device__ __forceinline__ unsigned int cvt_pk_bf16(float a, float b) {
  unsigned int r;
  asm("v_cvt_pk_bf16_f32 %0, %1, %2" : "=v"(r) : "v"(a), "v"(b));
  return r;
}

#define ASYNC_LDS16(g, l) \
  __builtin_amdgcn_global_load_lds((const __attribute__((address_space(1))) void*)(g), \
                                   (__attribute__((address_space(3))) void*)(l), 16, 0, 0)

// ---------------------------------------------------------------------------
// K1: modality splice + norm + gamma, write xn bf16 [4096][1024]
// ---------------------------------------------------------------------------
__global__ __launch_bounds__(256) void k_prep(const float* __restrict__ x,
                                              const float* __restrict__ tokens,
                                              const float* __restrict__ gamma,
                                              const int* __restrict__ mods,
                                              unsigned short* __restrict__ xn) {
  int bs = blockIdx.x;
  int bb = bs / NN, s = bs % NN;
  int t = threadIdx.x;
  int c = t * 4;
  const float4 xv = *(const float4*)(x + (size_t)bs * DD + c);
  float4 acc = {0.f, 0.f, 0.f, 0.f};
  bool any = false;
  #pragma unroll
  for (int m = 0; m < MMOD; ++m) {
    int off = mods[(bb * MMOD + m) * 3 + 1];
    int ln  = mods[(bb * MMOD + m) * 3 + 2];
    if (s >= off && s < off + ln) {
      any = true;
      int rel = s - off;
      if (rel > LMAX - 1) rel = LMAX - 1;
      if (rel < 0) rel = 0;
      const float4 tv = *(const float4*)(tokens + ((size_t)(bb * MMOD + m) * LMAX + rel) * DD + c);
      acc.x += tv.x; acc.y += tv.y; acc.z += tv.z; acc.w += tv.w;
    }
  }
  float4 v = any ? acc : xv;
  float ss = v.x*v.x + v.y*v.y + v.z*v.z + v.w*v.w;
  #pragma unroll
  for (int o = 32; o; o >>= 1) ss += __shfl_xor(ss, o);
  __shared__ float red[4];
  int wv = t >> 6;
  if ((t & 63) == 0) red[wv] = ss;
  __syncthreads();
  float tot = red[0] + red[1] + red[2] + red[3];
  float norm = sqrtf(tot);
  norm = fmaxf(norm, 1e-12f);
  float sc = 32.0f / norm;   // sqrt(1024) = 32
  const float4 g = *(const float4*)(gamma + c);
  unsigned long long pk =
      (unsigned long long)f2bf(v.x * sc * (g.x + 1.f)) |
      ((unsigned long long)f2bf(v.y * sc * (g.y + 1.f)) << 16) |
      ((unsigned long long)f2bf(v.z * sc * (g.z + 1.f)) << 32) |
      ((unsigned long long)f2bf(v.w * sc * (g.w + 1.f)) << 48);
  *(unsigned long long*)(xn + (size_t)bs * DD + c) = pk;
}

// ---------------------------------------------------------------------------
// K2: pos[b][n] = s - cumsum(rot_any). One wave per batch.
// ---------------------------------------------------------------------------
__global__ void k_pos(const int* __restrict__ mods, int* __restrict__ pos) {
  int bb = blockIdx.x;
  int lane = threadIdx.x;       // 64
  int offs[MMOD], ends[MMOD];
  #pragma unroll
  for (int m = 0; m < MMOD; ++m) {
    int off = mods[(bb * MMOD + m) * 3 + 1];
    int ln  = mods[(bb * MMOD + m) * 3 + 2];
    offs[m] = off + 1;
    ends[m] = off + ln;
  }
  int base = lane * (NN / 64);  // 32 per lane
  int lc[NN / 64];
  int tot = 0;
  #pragma unroll
  for (int i = 0; i < NN / 64; ++i) {
    int s = base + i;
    int f = 0;
    #pragma unroll
    for (int m = 0; m < MMOD; ++m)
      if (s >= offs[m] && s < ends[m]) f = 1;
    tot += f;
    lc[i] = tot;
  }
  int v = tot;
  #pragma unroll
  for (int o = 1; o < 64; o <<= 1) {
    int u = __shfl_up(v, o);
    if (lane >= o) v += u;
  }
  int excl = v - tot;
  #pragma unroll
  for (int i = 0; i < NN / 64; ++i)
    pos[bb * NN + base + i] = base + i - (excl + lc[i]);
}

// ---------------------------------------------------------------------------
// K2b: RoPE cos/sin table [b*n][32] float2
// ---------------------------------------------------------------------------
__global__ void k_tab(const int* __restrict__ pos, float2* __restrict__ tab) {
  int gid = blockIdx.x * 256 + threadIdx.x;   // b*n*32 = 131072
  int p = gid & 31;
  int bs = gid >> 5;
  float inv = expf(-((float)p / 32.f) * 9.210340371976184f); // 1/10000^(2p/64)
  float ang = (float)pos[bs] * inv;
  float sn, cs;
  sincosf(ang, &sn, &cs);
  tab[gid] = make_float2(cs, sn);
}

// ---------------------------------------------------------------------------
// K3: merged weight transposes: f32 [R][C] -> bf16 [C][R] for both weights
// blocks 0..3071: w_qkv (96x32 tile grid); 3072..4095: w_out (32x32)
// ---------------------------------------------------------------------------
__global__ void k_tr2(const float* __restrict__ w_qkv, const float* __restrict__ w_out,
                      unsigned short* __restrict__ wqkvT, unsigned short* __restrict__ woutT) {
  __shared__ float tile[32][33];
  int bid = blockIdx.x;
  const float* in;
  unsigned short* out;
  int R, C, bx, by;
  if (bid < 3072) {
    in = w_qkv; out = wqkvT; R = DD; C = QKVN;
    bx = bid % 96; by = bid / 96;
  } else {
    int b2 = bid - 3072;
    in = w_out; out = woutT; R = HH * DHD; C = DD;
    bx = b2 % 32; by = b2 / 32;
  }
  int tx = threadIdx.x, ty = threadIdx.y;
  #pragma unroll
  for (int k = 0; k < 4; ++k) {
    int r = by * 32 + ty + k * 8, c = bx * 32 + tx;
    tile[ty + k * 8][tx] = in[(size_t)r * C + c];
  }
  __syncthreads();
  #pragma unroll
  for (int k = 0; k < 4; ++k) {
    int oc = bx * 32 + ty + k * 8;
    int orr = by * 32 + tx;
    out[(size_t)oc * R + orr] = f2bf(tile[tx][ty + k * 8]);
  }
}

// ---------------------------------------------------------------------------
// K4: QKV GEMM 128x128, BK=64, 4 waves, dbuf LDS + XOR swz + XCD swizzle.
// ---------------------------------------------------------------------------
template<bool F32OUT>
__global__ __launch_bounds__(256) void k_gemm(const unsigned short* __restrict__ A,
                                              const unsigned short* __restrict__ Bt,
                                              void* __restrict__ Cp,
                                              int M, int Nn, int K) {
  __shared__ unsigned short As[2][128 * 64];
  __shared__ unsigned short Bs[2][128 * 64];
  int tid = threadIdx.x;
  int lane = tid & 63, wv = tid >> 6;
  int lo = lane & 15, hi = lane >> 4;
  int nb = gridDim.x * gridDim.y;
  int fid = blockIdx.y * gridDim.x + blockIdx.x;
  int cpx = nb >> 3;
  int nid = (fid & 7) * cpx + (fid >> 3);      // contiguous chunk per XCD
  int m0 = (nid / gridDim.x) * 128;
  int n0 = (nid % gridDim.x) * 128;
  int wr = wv >> 1, wc = wv & 1;
  f32x4 acc[4][4] = {};

  int srow = tid >> 3;
  int scs  = ((tid & 7) ^ ((tid >> 3) & 7)) * 8;
  #define STAGE_G(BUF, KT) do { \
    _Pragma("unroll") \
    for (int is_ = 0; is_ < 4; ++is_) { \
      int r_ = is_ * 32 + srow; \
      const unsigned short* ga_ = A  + (size_t)(m0 + r_) * K + (KT) + scs; \
      const unsigned short* gb_ = Bt + (size_t)(n0 + r_) * K + (KT) + scs; \
      ASYNC_LDS16(ga_, &As[BUF][(is_ * 256 + wv * 64) * 8]); \
      ASYNC_LDS16(gb_, &Bs[BUF][(is_ * 256 + wv * 64) * 8]); \
    } \
  } while (0)

  int nt = K >> 6;
  STAGE_G(0, 0);
  __syncthreads();
  int buf = 0;
  for (int t = 0; t < nt; ++t) {
    if (t + 1 < nt) STAGE_G(buf ^ 1, (t + 1) << 6);
    #pragma unroll
    for (int ks = 0; ks < 2; ++ks) {
      s16x8 af[4], bfr[4];
      #pragma unroll
      for (int m = 0; m < 4; ++m) {
        int row = wr * 64 + m * 16 + lo;
        int cc = ((ks * 4 + hi) ^ (lo & 7)) * 8;
        af[m] = *(const s16x8*)&As[buf][row * 64 + cc];
      }
      #pragma unroll
      for (int nn = 0; nn < 4; ++nn) {
        int row = wc * 64 + nn * 16 + lo;
        int cc = ((ks * 4 + hi) ^ (lo & 7)) * 8;
        bfr[nn] = *(const s16x8*)&Bs[buf][row * 64 + cc];
      }
      #pragma unroll
      for (int m = 0; m < 4; ++m)
        #pragma unroll
        for (int nn = 0; nn < 4; ++nn)
          acc[m][nn] = __builtin_amdgcn_mfma_f32_16x16x32_bf16(af[m], bfr[nn], acc[m][nn], 0, 0, 0);
    }
    __syncthreads();
    buf ^= 1;
  }
  #undef STAGE_G

  #pragma unroll
  for (int m = 0; m < 4; ++m) {
    #pragma unroll
    for (int nn = 0; nn < 4; ++nn) {
      int r0 = m0 + wr * 64 + m * 16 + hi * 4;
      int cc = n0 + wc * 64 + nn * 16 + lo;
      #pragma unroll
      for (int j = 0; j < 4; ++j) {
        float val = acc[m][nn][j];
        if (F32OUT) ((float*)Cp)[(size_t)(r0 + j) * Nn + cc] = val;
        else        ((unsigned short*)Cp)[(size_t)(r0 + j) * Nn + cc] = f2bf(val);
      }
    }
  }
}

// ---------------------------------------------------------------------------
// K7: out-proj GEMM, BM=128 BN=64 (grid 512), 4 waves stacked, acc[2][4].
// ---------------------------------------------------------------------------
template<bool F32OUT>
__global__ __launch_bounds__(256) void k_gemm_n64(const unsigned short* __restrict__ A,
                                                  const unsigned short* __restrict__ Bt,
                                                  void* __restrict__ Cp,
                                                  int M, int Nn, int K) {
  __shared__ unsigned short As[2][128 * 64];
  __shared__ unsigned short Bs[2][64 * 64];
  int tid = threadIdx.x;
  int lane = tid & 63, wv = tid >> 6;
  int lo = lane & 15, hi = lane >> 4;
  int nb = gridDim.x * gridDim.y;
  int fid = blockIdx.y * gridDim.x + blockIdx.x;
  int cpx = nb >> 3;
  int nid = (fid & 7) * cpx + (fid >> 3);
  int m0 = (nid / gridDim.x) * 128;
  int n0 = (nid % gridDim.x) * 64;
  f32x4 acc[2][4] = {};

  int srow = tid >> 3;
  int scs  = ((tid & 7) ^ ((tid >> 3) & 7)) * 8;
  #define STAGE_N(BUF, KT) do { \
    _Pragma("unroll") \
    for (int is_ = 0; is_ < 4; ++is_) { \
      int r_ = is_ * 32 + srow; \
      const unsigned short* ga_ = A + (size_t)(m0 + r_) * K + (KT) + scs; \
      ASYNC_LDS16(ga_, &As[BUF][(is_ * 256 + wv * 64) * 8]); \
    } \
    _Pragma("unroll") \
    for (int is_ = 0; is_ < 2; ++is_) { \
      int r_ = is_ * 32 + srow; \
      const unsigned short* gb_ = Bt + (size_t)(n0 + r_) * K + (KT) + scs; \
      ASYNC_LDS16(gb_, &Bs[BUF][(is_ * 256 + wv * 64) * 8]); \
    } \
  } while (0)

  int nt = K >> 6;
  STAGE_N(0, 0);
  __syncthreads();
  int buf = 0;
  for (int t = 0; t < nt; ++t) {
    if (t + 1 < nt) STAGE_N(buf ^ 1, (t + 1) << 6);
    #pragma unroll
    for (int ks = 0; ks < 2; ++ks) {
      s16x8 af[2], bfr[4];
      #pragma unroll
      for (int m = 0; m < 2; ++m) {
        int row = wv * 32 + m * 16 + lo;
        int cc = ((ks * 4 + hi) ^ (lo & 7)) * 8;
        af[m] = *(const s16x8*)&As[buf][row * 64 + cc];
      }
      #pragma unroll
      for (int nn = 0; nn < 4; ++nn) {
        int row = nn * 16 + lo;
        int cc = ((ks * 4 + hi) ^ (lo & 7)) * 8;
        bfr[nn] = *(const s16x8*)&Bs[buf][row * 64 + cc];
      }
      #pragma unroll
      for (int m = 0; m < 2; ++m)
        #pragma unroll
        for (int nn = 0; nn < 4; ++nn)
          acc[m][nn] = __builtin_amdgcn_mfma_f32_16x16x32_bf16(af[m], bfr[nn], acc[m][nn], 0, 0, 0);
    }
    __syncthreads();
    buf ^= 1;
  }
  #undef STAGE_N

  #pragma unroll
  for (int m = 0; m < 2; ++m)
    #pragma unroll
    for (int nn = 0; nn < 4; ++nn) {
      int r0 = m0 + wv * 32 + m * 16 + hi * 4;
      int cc = n0 + nn * 16 + lo;
      #pragma unroll
      for (int j = 0; j < 4; ++j) {
        float val = acc[m][nn][j];
        if (F32OUT) ((float*)Cp)[(size_t)(r0 + j) * Nn + cc] = val;
        else        ((unsigned short*)Cp)[(size_t)(r0 + j) * Nn + cc] = f2bf(val);
      }
    }
}

// ---------------------------------------------------------------------------
// K5: merged K-RoPE + V transpose.
// blocks 0..4095: RoPE K (qkvt cols 1024..2047 -> kd)
// blocks 4096..5119: V -> sigma-permuted vT
// sigma(k): bits [b5 b4 b3 b2 b1 b0] -> 32*b5 + 16*b3 + 8*b2 + 4*b4 + b1b0
// ---------------------------------------------------------------------------
__global__ __launch_bounds__(256) void k_ropevtr(const unsigned short* __restrict__ qkvt,
                                                 const float2* __restrict__ tab,
                                                 unsigned short* __restrict__ kd,
                                                 unsigned short* __restrict__ vT) {
  __shared__ unsigned short t[64][72];
  int bid = blockIdx.x;
  if (bid < BNROWS) {
    int bs = bid;
    int bb = bs / NN, s = bs % NN;
    int lane = threadIdx.x & 63, wv = threadIdx.x >> 6;
    #pragma unroll
    for (int g = 16 + wv; g < 32; g += 4) {
      int h = g & 15;
      float val = bf2f(qkvt[(size_t)bs * QKVN + g * 64 + lane]);
      float partner = __shfl_xor(val, 1);
      float2 cs = tab[(size_t)bs * 32 + (lane >> 1)];
      float out;
      if ((lane & 1) == 0) out = val * cs.x - partner * cs.y;    // t1*cos - t2*sin
      else                 out = partner * cs.y + val * cs.x;    // t1*sin + t2*cos
      kd[((size_t)(bb * HH + h) * NN + s) * 64 + lane] = f2bf(out);
    }
  } else {
    int idx = bid - BNROWS;
    int s0 = (idx & 31) * 64, bh = idx >> 5, bb = bh >> 4, h = bh & 15;
    int tid = threadIdx.x;
    int r = tid >> 2, c0 = (tid & 3) * 16;
    int cw = c0 ^ (((r >> 4) & 3) << 4);
    const unsigned short* src = qkvt + (size_t)(bb * NN + s0 + r) * QKVN + 2048 + h * 64 + c0;
    *(s16x8*)&t[r][cw]     = *(const s16x8*)src;
    *(s16x8*)&t[r][cw + 8] = *(const s16x8*)(src + 8);
    __syncthreads();
    int dh = tid >> 2, sc = (tid & 3) * 16;
    int col2 = dh ^ ((tid & 3) << 4);
    s16x8 o1, o2;
    #pragma unroll
    for (int i = 0; i < 8; ++i) {
      o1[i] = (short)t[sc + i][col2];
      o2[i] = (short)t[sc + 8 + i][col2];
    }
    unsigned short* dst = vT + ((size_t)bh * 64 + dh) * NN + s0;
    int pb = (sc & 32) + (((sc >> 4) & 1) << 2);
    s16x4 g0 = __builtin_shufflevector(o1, o1, 0, 1, 2, 3);
    s16x4 g1 = __builtin_shufflevector(o1, o1, 4, 5, 6, 7);
    s16x4 g2 = __builtin_shufflevector(o2, o2, 0, 1, 2, 3);
    s16x4 g3 = __builtin_shufflevector(o2, o2, 4, 5, 6, 7);
    *(s16x4*)&dst[pb]      = g0;
    *(s16x4*)&dst[pb + 8]  = g1;
    *(s16x4*)&dst[pb + 16] = g2;
    *(s16x4*)&dst[pb + 24] = g3;
  }
}

// ---------------------------------------------------------------------------
// K6: flash attention (R14 exact). KVBLK=128, 8 waves, paired long/short
// q-tiles (XCD-contiguous map), dbuf K/V staging, swapped QK^T, cvt_pk P,
// PV b128 from XOR-swizzled sigma-permuted vT, in-register Q-RoPE.
// ---------------------------------------------------------------------------
__global__ __launch_bounds__(512) void k_attn(const unsigned short* __restrict__ qkvt,
                                              const float2* __restrict__ tab,
                                              const unsigned short* __restrict__ k,
                                              const unsigned short* __restrict__ vT,
                                              const int* __restrict__ mods,
                                              unsigned short* __restrict__ o) {
  __shared__ unsigned short Ks[2][128 * 64];   // 128 keys x 64 dh
  __shared__ unsigned short Vs[2][64 * 128];   // 64 dh x 128 keys
  int tid = threadIdx.x;
  int lane = tid & 63, wv = tid >> 6;
  int lo = lane & 15, hi = lane >> 4;

  int fid = blockIdx.y * gridDim.x + blockIdx.x;      // 0..511
  int nid = (fid & 7) * 64 + (fid >> 3);              // XCD-contiguous (R12)
  int bh = nid >> 4;
  int bx = nid & 15;
  int bb = bh >> 4;
  int h = bh & 15;
  int q0A = (31 - bx) * 64;                           // long tile
  int q0B = bx * 64;                                  // mirror short tile
  int q0w = ((wv < 4) ? q0A : q0B) + (wv & 3) * 16;

  const unsigned short* kb = k + (size_t)bh * NN * 64;
  const unsigned short* vb = vT + (size_t)bh * 64 * NN;

  // Q fragments: raw GEMM output + in-register RoPE (pairs are adjacent).
  s16x8 qf[2];
  {
    int qrow = q0w + lo;
    const unsigned short* qp = qkvt + (size_t)(bb * NN + qrow) * QKVN + h * 64;
    const float2* tb = tab + (size_t)(bb * NN + qrow) * 32;
    #pragma unroll
    for (int ks = 0; ks < 2; ++ks) {
      s16x8 raw = *(const s16x8*)&qp[ks * 32 + hi * 8];
      #pragma unroll
      for (int e2 = 0; e2 < 4; ++e2) {
        float2 cs = tb[ks * 16 + hi * 4 + e2];
        float t1 = bf2f((unsigned short)raw[2 * e2]);
        float t2 = bf2f((unsigned short)raw[2 * e2 + 1]);
        float o1 = (t1 * cs.x - t2 * cs.y) * 0.18033688011112042f; // 0.125*log2e
        float o2 = (t1 * cs.y + t2 * cs.x) * 0.18033688011112042f;
        qf[ks][2 * e2]     = (short)f2bf(o1);
        qf[ks][2 * e2 + 1] = (short)f2bf(o2);
      }
    }
  }

  int off_[MMOD], end_[MMOD];
  #pragma unroll
  for (int m = 0; m < MMOD; ++m) {
    off_[m] = mods[(bb * MMOD + m) * 3 + 1];
    end_[m] = off_[m] + mods[(bb * MMOD + m) * 3 + 2];
  }
  int limit_l;
  {
    int r = q0w + lo;
    int L = r + 1;
    #pragma unroll
    for (int m = 0; m < MMOD; ++m)
      if (off_[m] <= r && end_[m] > L) L = end_[m];
    limit_l = L;
  }
  int minlim, kvmax_w;
  {
    int L = q0w + 1;
    #pragma unroll
    for (int m = 0; m < MMOD; ++m)
      if (off_[m] <= q0w && end_[m] > L) L = end_[m];
    minlim = L;
    int r = q0w + 15;
    int L2 = r + 1;
    #pragma unroll
    for (int m = 0; m < MMOD; ++m)
      if (off_[m] <= r && end_[m] > L2) L2 = end_[m];
    kvmax_w = L2;
  }
  int nt;
  {
    int ra = q0A + 63;
    int LA = ra + 1;
    #pragma unroll
    for (int m = 0; m < MMOD; ++m)
      if (off_[m] <= ra && end_[m] > LA) LA = end_[m];
    int rb2 = q0B + 63;
    int LB = rb2 + 1;
    #pragma unroll
    for (int m = 0; m < MMOD; ++m)
      if (off_[m] <= rb2 && end_[m] > LB) LB = end_[m];
    int Lblk = (LA > LB) ? LA : LB;
    nt = (Lblk + 127) >> 7;
  }

  // Stage 128-key K/V tile: 2 shots x 512 threads x 16B for each of K,V.
  #define STAGE_KV(B, KV0) do { \
    _Pragma("unroll") \
    for (int i_ = 0; i_ < 2; ++i_) { \
      int rK_ = i_ * 64 + (tid >> 3); \
      int csK_ = (lane & 7) ^ ((tid >> 3) & 7); \
      const unsigned short* gK_ = kb + (size_t)((KV0) + rK_) * 64 + csK_ * 8; \
      ASYNC_LDS16(gK_, &Ks[B][(i_ * 512 + wv * 64) * 8]); \
      int dhV_ = i_ * 32 + wv * 4 + (lane >> 4); \
      int ccV_ = ((lane & 7) ^ (dhV_ & 7)) | (lane & 8); \
      const unsigned short* gV_ = vb + (size_t)dhV_ * NN + (KV0) + ccV_ * 8; \
      ASYNC_LDS16(gV_, &Vs[B][(i_ * 512 + wv * 64) * 8]); \
    } \
  } while (0)

  float lr = 0.f;
  f32x4 accO[4] = {};

  STAGE_KV(0, 0);
  __syncthreads();
  int buf = 0;
  for (int t = 0; t < nt; ++t) {
    if (t + 1 < nt) STAGE_KV(buf ^ 1, (t + 1) << 7);
    int kv0 = t << 7;
    if (kv0 < kvmax_w) {
      // S^T = K Q^T; sv[cb][j] = S[qrow=lo][key=kv0+cb*16+hi*4+j], cb 0..7
      f32x4 sv[8];
      __builtin_amdgcn_s_setprio(1);
      #pragma unroll
      for (int cb = 0; cb < 8; ++cb) {
        int krow = cb * 16 + lo;
        int c0 = (hi) ^ (krow & 7);
        int c1 = (4 + hi) ^ (krow & 7);
        s16x8 kf0 = *(const s16x8*)&Ks[buf][krow * 64 + c0 * 8];
        s16x8 kf1 = *(const s16x8*)&Ks[buf][krow * 64 + c1 * 8];
        f32x4 z = {};
        z = __builtin_amdgcn_mfma_f32_16x16x32_bf16(kf0, qf[0], z, 0, 0, 0);
        z = __builtin_amdgcn_mfma_f32_16x16x32_bf16(kf1, qf[1], z, 0, 0, 0);
        sv[cb] = z;
      }
      __builtin_amdgcn_s_setprio(0);

      // p = exp2(sv - sv^3*k2)  (== exp(s - s^3/7500), e^-50 shift cancels)
      unsigned int pk_[8][2];
      bool edge = (kv0 + 128 > minlim);
      int kb0 = kv0 + hi * 4;
      #pragma unroll
      for (int cb = 0; cb < 8; ++cb) {
        float p[4];
        #pragma unroll
        for (int j = 0; j < 4; ++j) {
          float s = sv[cb][j];
          float u = __builtin_fmaf(s * s, -6.40604e-5f, 1.0f);
          float pp = __builtin_amdgcn_exp2f(s * u);
          if (edge && (kb0 + cb * 16 + j) >= limit_l) pp = 0.f;
          p[j] = pp;
        }
        lr += (p[0] + p[1]) + (p[2] + p[3]);
        pk_[cb][0] = cvt_pk_bf16(p[0], p[1]);
        pk_[cb][1] = cvt_pk_bf16(p[2], p[3]);
      }

      // pa[ks'] covers keys of cb = ks'*2 .. ks'*2+1 groups (sigma order)
      union { unsigned int u[4]; s16x8 v; } pa[4];
      #pragma unroll
      for (int kk = 0; kk < 4; ++kk) {
        pa[kk].u[0] = pk_[2 * kk][0];
        pa[kk].u[1] = pk_[2 * kk][1];
        pa[kk].u[2] = pk_[2 * kk + 1][0];
        pa[kk].u[3] = pk_[2 * kk + 1][1];
      }

      // PV from swizzled LDS (row stride 128): conflict-free b128 reads
      __builtin_amdgcn_s_setprio(1);
      #pragma unroll
      for (int ks = 0; ks < 4; ++ks) {
        #pragma unroll
        for (int cbo = 0; cbo < 4; ++cbo) {
          int vrow = cbo * 16 + lo;
          int vc = (ks * 4 + hi) ^ (vrow & 7);
          s16x8 vf = *(const s16x8*)&Vs[buf][vrow * 128 + vc * 8];
          accO[cbo] = __builtin_amdgcn_mfma_f32_16x16x32_bf16(pa[ks].v, vf, accO[cbo], 0, 0, 0);
        }
      }
      __builtin_amdgcn_s_setprio(0);
    }
    __syncthreads();
    buf ^= 1;
  }

  // denominator: total for qrow=lo, redistribute to output rows hi*4+j
  lr += __shfl_xor(lr, 16);
  lr += __shfl_xor(lr, 32);
  float rl[4];
  #pragma unroll
  for (int j = 0; j < 4; ++j)
    rl[j] = __builtin_amdgcn_rcpf(__shfl(lr, hi * 4 + j));

  #pragma unroll
  for (int cb = 0; cb < 4; ++cb)
    #pragma unroll
    for (int j = 0; j < 4; ++j) {
      int r = q0w + hi * 4 + j;
      float val = accO[cb][j] * rl[j];
      o[((size_t)(bb * NN) + r) * (HH * DHD) + h * 64 + cb * 16 + lo] = f2bf(val);
    }
}

// ---------------------------------------------------------------------------
extern "C" void kernel_launch(void* const* d_in, const int* in_sizes, int n_in,
                              void* d_out, int out_size, void* d_ws, size_t ws_size,
                              hipStream_t stream) {
  (void)in_sizes; (void)n_in; (void)out_size; (void)ws_size;
  const float* x      = (const float*)d_in[0];
  const float* tokens = (const float*)d_in[1];
  const float* gamma  = (const float*)d_in[2];
  const float* w_qkv  = (const float*)d_in[3];
  const float* w_out  = (const float*)d_in[4];
  const int*   mods   = (const int*)d_in[5];

  char* ws = (char*)d_ws;
  unsigned short* xn    = (unsigned short*)(ws + 0);           //  8 MB
  unsigned short* wqkvT = (unsigned short*)(ws + 8388608);     //  6 MB
  unsigned short* woutT = (unsigned short*)(ws + 14680064);    //  2 MB
  unsigned short* qkvt  = (unsigned short*)(ws + 16777216);    // 24 MB
  unsigned short* kd    = (unsigned short*)(ws + 50331648);    //  8 MB
  unsigned short* vTd   = (unsigned short*)(ws + 58720256);    //  8 MB
  unsigned short* attno = (unsigned short*)(ws + 67108864);    //  8 MB
  int*            pos   = (int*)(ws + 75497472);               // 16 KB
  float2*         tab   = (float2*)(ws + 75513856);            //  1 MB

  k_prep<<<BNROWS, 256, 0, stream>>>(x, tokens, gamma, mods, xn);
  k_pos<<<BB, 64, 0, stream>>>(mods, pos);
  k_tab<<<(BB * NN * 32) / 256, 256, 0, stream>>>(pos, tab);
  k_tr2<<<4096, dim3(32, 8), 0, stream>>>(w_qkv, w_out, wqkvT, woutT);
  k_gemm<false><<<dim3(QKVN / 128, BNROWS / 128), 256, 0, stream>>>(xn, wqkvT, (void*)qkvt, BNROWS, QKVN, DD);
  k_ropevtr<<<BNROWS + 1024, 256, 0, stream>>>(qkvt, tab, kd, vTd);
  k_attn<<<dim3(16, BB * HH), 512, 0, stream>>>(qkvt, tab, kd, vTd, mods, attno);
  k_gemm_n64<true><<<dim3(DD / 64, BNROWS / 128), 256, 0, stream>>>(attno, woutT, (void*)d_out, BNROWS, DD, HH * DHD);
}

// Round 19
// 125.622 us; speedup vs baseline: 1.2170x; 1.0502x over previous
//
#include <hip/hip_runtime.h>
#include <stdint.h>

#define HH 16
#define DHD 64
#define BB 2
#define NN 2048
#define DD 1024
#define MMOD 4
#define LMAX 256
#define BNROWS (BB*NN)      // 4096
#define QKVN (3*HH*DHD)     // 3072

typedef __attribute__((ext_vector_type(4))) float f32x4;
typedef __attribute__((ext_vector_type(8))) short s16x8;
typedef __attribute__((ext_vector_type(4))) short s16x4;

__device__ __forceinline__ float bf2f(unsigned short b) {
  return __uint_as_float(((unsigned int)b) << 16);
}
__device__ __forceinline__ unsigned short f2bf(float f) {
  unsigned int u = __float_as_uint(f);
  u += 0x7fffu + ((u >> 16) & 1u);
  return (unsigned short)(u >> 16);
}
__device__ __forceinline__ unsigned int cvt_pk_bf16(float a, float b) {
  unsigned int r;
  asm("v_cvt_pk_bf16_f32 %0, %1, %2" : "=v"(r) : "v"(a), "v"(b));
  return r;
}

#define ASYNC_LDS16(g, l) \
  __builtin_amdgcn_global_load_lds((const __attribute__((address_space(1))) void*)(g), \
                                   (__attribute__((address_space(3))) void*)(l), 16, 0, 0)

// ---------------------------------------------------------------------------
// K1: modality splice + norm + gamma, write xn bf16 [4096][1024]
// ---------------------------------------------------------------------------
__global__ __launch_bounds__(256) void k_prep(const float* __restrict__ x,
                                              const float* __restrict__ tokens,
                                              const float* __restrict__ gamma,
                                              const int* __restrict__ mods,
                                              unsigned short* __restrict__ xn) {
  int bs = blockIdx.x;
  int bb = bs / NN, s = bs % NN;
  int t = threadIdx.x;
  int c = t * 4;
  const float4 xv = *(const float4*)(x + (size_t)bs * DD + c);
  float4 acc = {0.f, 0.f, 0.f, 0.f};
  bool any = false;
  #pragma unroll
  for (int m = 0; m < MMOD; ++m) {
    int off = mods[(bb * MMOD + m) * 3 + 1];
    int ln  = mods[(bb * MMOD + m) * 3 + 2];
    if (s >= off && s < off + ln) {
      any = true;
      int rel = s - off;
      if (rel > LMAX - 1) rel = LMAX - 1;
      if (rel < 0) rel = 0;
      const float4 tv = *(const float4*)(tokens + ((size_t)(bb * MMOD + m) * LMAX + rel) * DD + c);
      acc.x += tv.x; acc.y += tv.y; acc.z += tv.z; acc.w += tv.w;
    }
  }
  float4 v = any ? acc : xv;
  float ss = v.x*v.x + v.y*v.y + v.z*v.z + v.w*v.w;
  #pragma unroll
  for (int o = 32; o; o >>= 1) ss += __shfl_xor(ss, o);
  __shared__ float red[4];
  int wv = t >> 6;
  if ((t & 63) == 0) red[wv] = ss;
  __syncthreads();
  float tot = red[0] + red[1] + red[2] + red[3];
  float norm = sqrtf(tot);
  norm = fmaxf(norm, 1e-12f);
  float sc = 32.0f / norm;   // sqrt(1024) = 32
  const float4 g = *(const float4*)(gamma + c);
  unsigned long long pk =
      (unsigned long long)f2bf(v.x * sc * (g.x + 1.f)) |
      ((unsigned long long)f2bf(v.y * sc * (g.y + 1.f)) << 16) |
      ((unsigned long long)f2bf(v.z * sc * (g.z + 1.f)) << 32) |
      ((unsigned long long)f2bf(v.w * sc * (g.w + 1.f)) << 48);
  *(unsigned long long*)(xn + (size_t)bs * DD + c) = pk;
}

// ---------------------------------------------------------------------------
// K2: pos[b][n] = s - cumsum(rot_any). One wave per batch.
// ---------------------------------------------------------------------------
__global__ void k_pos(const int* __restrict__ mods, int* __restrict__ pos) {
  int bb = blockIdx.x;
  int lane = threadIdx.x;       // 64
  int offs[MMOD], ends[MMOD];
  #pragma unroll
  for (int m = 0; m < MMOD; ++m) {
    int off = mods[(bb * MMOD + m) * 3 + 1];
    int ln  = mods[(bb * MMOD + m) * 3 + 2];
    offs[m] = off + 1;
    ends[m] = off + ln;
  }
  int base = lane * (NN / 64);  // 32 per lane
  int lc[NN / 64];
  int tot = 0;
  #pragma unroll
  for (int i = 0; i < NN / 64; ++i) {
    int s = base + i;
    int f = 0;
    #pragma unroll
    for (int m = 0; m < MMOD; ++m)
      if (s >= offs[m] && s < ends[m]) f = 1;
    tot += f;
    lc[i] = tot;
  }
  int v = tot;
  #pragma unroll
  for (int o = 1; o < 64; o <<= 1) {
    int u = __shfl_up(v, o);
    if (lane >= o) v += u;
  }
  int excl = v - tot;
  #pragma unroll
  for (int i = 0; i < NN / 64; ++i)
    pos[bb * NN + base + i] = base + i - (excl + lc[i]);
}

// ---------------------------------------------------------------------------
// K2b: RoPE cos/sin table [b*n][32] float2
// ---------------------------------------------------------------------------
__global__ void k_tab(const int* __restrict__ pos, float2* __restrict__ tab) {
  int gid = blockIdx.x * 256 + threadIdx.x;   // b*n*32 = 131072
  int p = gid & 31;
  int bs = gid >> 5;
  float inv = expf(-((float)p / 32.f) * 9.210340371976184f); // 1/10000^(2p/64)
  float ang = (float)pos[bs] * inv;
  float sn, cs;
  sincosf(ang, &sn, &cs);
  tab[gid] = make_float2(cs, sn);
}

// ---------------------------------------------------------------------------
// K3: merged weight transposes: f32 [R][C] -> bf16 [C][R] for both weights
// blocks 0..3071: w_qkv (96x32 tile grid); 3072..4095: w_out (32x32)
// ---------------------------------------------------------------------------
__global__ void k_tr2(const float* __restrict__ w_qkv, const float* __restrict__ w_out,
                      unsigned short* __restrict__ wqkvT, unsigned short* __restrict__ woutT) {
  __shared__ float tile[32][33];
  int bid = blockIdx.x;
  const float* in;
  unsigned short* out;
  int R, C, bx, by;
  if (bid < 3072) {
    in = w_qkv; out = wqkvT; R = DD; C = QKVN;
    bx = bid % 96; by = bid / 96;
  } else {
    int b2 = bid - 3072;
    in = w_out; out = woutT; R = HH * DHD; C = DD;
    bx = b2 % 32; by = b2 / 32;
  }
  int tx = threadIdx.x, ty = threadIdx.y;
  #pragma unroll
  for (int k = 0; k < 4; ++k) {
    int r = by * 32 + ty + k * 8, c = bx * 32 + tx;
    tile[ty + k * 8][tx] = in[(size_t)r * C + c];
  }
  __syncthreads();
  #pragma unroll
  for (int k = 0; k < 4; ++k) {
    int oc = bx * 32 + ty + k * 8;
    int orr = by * 32 + tx;
    out[(size_t)oc * R + orr] = f2bf(tile[tx][ty + k * 8]);
  }
}

// ---------------------------------------------------------------------------
// K4: QKV GEMM, BM=128 BN=192 BK=64, 4 waves (2x2, wave tile 64x96),
// acc[4][6], 80 KB LDS -> 2 blocks/CU; grid 512 = exactly one resident
// round. dbuf + XOR swz + chunked XCD swizzle. bf16 out.
// ---------------------------------------------------------------------------
__global__ __launch_bounds__(256) void k_gemmq(const unsigned short* __restrict__ A,
                                               const unsigned short* __restrict__ Bt,
                                               unsigned short* __restrict__ C,
                                               int M, int Nn, int K) {
  __shared__ unsigned short As[2][128 * 64];
  __shared__ unsigned short Bs[2][192 * 64];
  int tid = threadIdx.x;
  int lane = tid & 63, wv = tid >> 6;
  int lo = lane & 15, hi = lane >> 4;
  int nb = gridDim.x * gridDim.y;              // 512
  int fid = blockIdx.y * gridDim.x + blockIdx.x;
  int cpx = nb >> 3;
  int nid = (fid & 7) * cpx + (fid >> 3);      // contiguous chunk per XCD
  int m0 = (nid / gridDim.x) * 128;
  int n0 = (nid % gridDim.x) * 192;
  int wr = wv >> 1, wc = wv & 1;
  f32x4 acc[4][6] = {};

  int srow = tid >> 3;
  int scs  = ((tid & 7) ^ ((tid >> 3) & 7)) * 8;
  #define STAGE_Q(BUF, KT) do { \
    _Pragma("unroll") \
    for (int is_ = 0; is_ < 4; ++is_) { \
      int r_ = is_ * 32 + srow; \
      const unsigned short* ga_ = A + (size_t)(m0 + r_) * K + (KT) + scs; \
      ASYNC_LDS16(ga_, &As[BUF][(is_ * 256 + tid) * 8]); \
    } \
    _Pragma("unroll") \
    for (int is_ = 0; is_ < 6; ++is_) { \
      int r_ = is_ * 32 + srow; \
      const unsigned short* gb_ = Bt + (size_t)(n0 + r_) * K + (KT) + scs; \
      ASYNC_LDS16(gb_, &Bs[BUF][(is_ * 256 + tid) * 8]); \
    } \
  } while (0)

  int nt = K >> 6;
  STAGE_Q(0, 0);
  __syncthreads();
  int buf = 0;
  for (int t = 0; t < nt; ++t) {
    if (t + 1 < nt) STAGE_Q(buf ^ 1, (t + 1) << 6);
    #pragma unroll
    for (int ks = 0; ks < 2; ++ks) {
      s16x8 af[4], bfr[6];
      #pragma unroll
      for (int m = 0; m < 4; ++m) {
        int row = wr * 64 + m * 16 + lo;
        int cc = ((ks * 4 + hi) ^ (lo & 7)) * 8;
        af[m] = *(const s16x8*)&As[buf][row * 64 + cc];
      }
      #pragma unroll
      for (int nn = 0; nn < 6; ++nn) {
        int row = wc * 96 + nn * 16 + lo;
        int cc = ((ks * 4 + hi) ^ (lo & 7)) * 8;
        bfr[nn] = *(const s16x8*)&Bs[buf][row * 64 + cc];
      }
      #pragma unroll
      for (int m = 0; m < 4; ++m)
        #pragma unroll
        for (int nn = 0; nn < 6; ++nn)
          acc[m][nn] = __builtin_amdgcn_mfma_f32_16x16x32_bf16(af[m], bfr[nn], acc[m][nn], 0, 0, 0);
    }
    __syncthreads();
    buf ^= 1;
  }
  #undef STAGE_Q

  #pragma unroll
  for (int m = 0; m < 4; ++m) {
    #pragma unroll
    for (int nn = 0; nn < 6; ++nn) {
      int r0 = m0 + wr * 64 + m * 16 + hi * 4;
      int cc = n0 + wc * 96 + nn * 16 + lo;
      #pragma unroll
      for (int j = 0; j < 4; ++j)
        C[(size_t)(r0 + j) * Nn + cc] = f2bf(acc[m][nn][j]);
    }
  }
}

// ---------------------------------------------------------------------------
// K7: out-proj GEMM, BM=128 BN=64 (grid 512), 4 waves stacked, acc[2][4].
// ---------------------------------------------------------------------------
template<bool F32OUT>
__global__ __launch_bounds__(256) void k_gemm_n64(const unsigned short* __restrict__ A,
                                                  const unsigned short* __restrict__ Bt,
                                                  void* __restrict__ Cp,
                                                  int M, int Nn, int K) {
  __shared__ unsigned short As[2][128 * 64];
  __shared__ unsigned short Bs[2][64 * 64];
  int tid = threadIdx.x;
  int lane = tid & 63, wv = tid >> 6;
  int lo = lane & 15, hi = lane >> 4;
  int nb = gridDim.x * gridDim.y;
  int fid = blockIdx.y * gridDim.x + blockIdx.x;
  int cpx = nb >> 3;
  int nid = (fid & 7) * cpx + (fid >> 3);
  int m0 = (nid / gridDim.x) * 128;
  int n0 = (nid % gridDim.x) * 64;
  f32x4 acc[2][4] = {};

  int srow = tid >> 3;
  int scs  = ((tid & 7) ^ ((tid >> 3) & 7)) * 8;
  #define STAGE_N(BUF, KT) do { \
    _Pragma("unroll") \
    for (int is_ = 0; is_ < 4; ++is_) { \
      int r_ = is_ * 32 + srow; \
      const unsigned short* ga_ = A + (size_t)(m0 + r_) * K + (KT) + scs; \
      ASYNC_LDS16(ga_, &As[BUF][(is_ * 256 + wv * 64) * 8]); \
    } \
    _Pragma("unroll") \
    for (int is_ = 0; is_ < 2; ++is_) { \
      int r_ = is_ * 32 + srow; \
      const unsigned short* gb_ = Bt + (size_t)(n0 + r_) * K + (KT) + scs; \
      ASYNC_LDS16(gb_, &Bs[BUF][(is_ * 256 + wv * 64) * 8]); \
    } \
  } while (0)

  int nt = K >> 6;
  STAGE_N(0, 0);
  __syncthreads();
  int buf = 0;
  for (int t = 0; t < nt; ++t) {
    if (t + 1 < nt) STAGE_N(buf ^ 1, (t + 1) << 6);
    #pragma unroll
    for (int ks = 0; ks < 2; ++ks) {
      s16x8 af[2], bfr[4];
      #pragma unroll
      for (int m = 0; m < 2; ++m) {
        int row = wv * 32 + m * 16 + lo;
        int cc = ((ks * 4 + hi) ^ (lo & 7)) * 8;
        af[m] = *(const s16x8*)&As[buf][row * 64 + cc];
      }
      #pragma unroll
      for (int nn = 0; nn < 4; ++nn) {
        int row = nn * 16 + lo;
        int cc = ((ks * 4 + hi) ^ (lo & 7)) * 8;
        bfr[nn] = *(const s16x8*)&Bs[buf][row * 64 + cc];
      }
      #pragma unroll
      for (int m = 0; m < 2; ++m)
        #pragma unroll
        for (int nn = 0; nn < 4; ++nn)
          acc[m][nn] = __builtin_amdgcn_mfma_f32_16x16x32_bf16(af[m], bfr[nn], acc[m][nn], 0, 0, 0);
    }
    __syncthreads();
    buf ^= 1;
  }
  #undef STAGE_N

  #pragma unroll
  for (int m = 0; m < 2; ++m)
    #pragma unroll
    for (int nn = 0; nn < 4; ++nn) {
      int r0 = m0 + wv * 32 + m * 16 + hi * 4;
      int cc = n0 + nn * 16 + lo;
      #pragma unroll
      for (int j = 0; j < 4; ++j) {
        float val = acc[m][nn][j];
        if (F32OUT) ((float*)Cp)[(size_t)(r0 + j) * Nn + cc] = val;
        else        ((unsigned short*)Cp)[(size_t)(r0 + j) * Nn + cc] = f2bf(val);
      }
    }
}

// ---------------------------------------------------------------------------
// K5: merged K-RoPE + V transpose.
// blocks 0..4095: RoPE K (qkvt cols 1024..2047 -> kd)
// blocks 4096..5119: V -> sigma-permuted vT
// sigma(k): bits [b5 b4 b3 b2 b1 b0] -> 32*b5 + 16*b3 + 8*b2 + 4*b4 + b1b0
// ---------------------------------------------------------------------------
__global__ __launch_bounds__(256) void k_ropevtr(const unsigned short* __restrict__ qkvt,
                                                 const float2* __restrict__ tab,
                                                 unsigned short* __restrict__ kd,
                                                 unsigned short* __restrict__ vT) {
  __shared__ unsigned short t[64][72];
  int bid = blockIdx.x;
  if (bid < BNROWS) {
    int bs = bid;
    int bb = bs / NN, s = bs % NN;
    int lane = threadIdx.x & 63, wv = threadIdx.x >> 6;
    #pragma unroll
    for (int g = 16 + wv; g < 32; g += 4) {
      int h = g & 15;
      float val = bf2f(qkvt[(size_t)bs * QKVN + g * 64 + lane]);
      float partner = __shfl_xor(val, 1);
      float2 cs = tab[(size_t)bs * 32 + (lane >> 1)];
      float out;
      if ((lane & 1) == 0) out = val * cs.x - partner * cs.y;    // t1*cos - t2*sin
      else                 out = partner * cs.y + val * cs.x;    // t1*sin + t2*cos
      kd[((size_t)(bb * HH + h) * NN + s) * 64 + lane] = f2bf(out);
    }
  } else {
    int idx = bid - BNROWS;
    int s0 = (idx & 31) * 64, bh = idx >> 5, bb = bh >> 4, h = bh & 15;
    int tid = threadIdx.x;
    int r = tid >> 2, c0 = (tid & 3) * 16;
    int cw = c0 ^ (((r >> 4) & 3) << 4);
    const unsigned short* src = qkvt + (size_t)(bb * NN + s0 + r) * QKVN + 2048 + h * 64 + c0;
    *(s16x8*)&t[r][cw]     = *(const s16x8*)src;
    *(s16x8*)&t[r][cw + 8] = *(const s16x8*)(src + 8);
    __syncthreads();
    int dh = tid >> 2, sc = (tid & 3) * 16;
    int col2 = dh ^ ((tid & 3) << 4);
    s16x8 o1, o2;
    #pragma unroll
    for (int i = 0; i < 8; ++i) {
      o1[i] = (short)t[sc + i][col2];
      o2[i] = (short)t[sc + 8 + i][col2];
    }
    unsigned short* dst = vT + ((size_t)bh * 64 + dh) * NN + s0;
    int pb = (sc & 32) + (((sc >> 4) & 1) << 2);
    s16x4 g0 = __builtin_shufflevector(o1, o1, 0, 1, 2, 3);
    s16x4 g1 = __builtin_shufflevector(o1, o1, 4, 5, 6, 7);
    s16x4 g2 = __builtin_shufflevector(o2, o2, 0, 1, 2, 3);
    s16x4 g3 = __builtin_shufflevector(o2, o2, 4, 5, 6, 7);
    *(s16x4*)&dst[pb]      = g0;
    *(s16x4*)&dst[pb + 8]  = g1;
    *(s16x4*)&dst[pb + 16] = g2;
    *(s16x4*)&dst[pb + 24] = g3;
  }
}

// ---------------------------------------------------------------------------
// K6: flash attention (R14 exact). KVBLK=128, 8 waves, paired long/short
// q-tiles (XCD-contiguous map), dbuf K/V staging, swapped QK^T, cvt_pk P,
// PV b128 from XOR-swizzled sigma-permuted vT, in-register Q-RoPE.
// ---------------------------------------------------------------------------
__global__ __launch_bounds__(512) void k_attn(const unsigned short* __restrict__ qkvt,
                                              const float2* __restrict__ tab,
                                              const unsigned short* __restrict__ k,
                                              const unsigned short* __restrict__ vT,
                                              const int* __restrict__ mods,
                                              unsigned short* __restrict__ o) {
  __shared__ unsigned short Ks[2][128 * 64];   // 128 keys x 64 dh
  __shared__ unsigned short Vs[2][64 * 128];   // 64 dh x 128 keys
  int tid = threadIdx.x;
  int lane = tid & 63, wv = tid >> 6;
  int lo = lane & 15, hi = lane >> 4;

  int fid = blockIdx.y * gridDim.x + blockIdx.x;      // 0..511
  int nid = (fid & 7) * 64 + (fid >> 3);              // XCD-contiguous (R12)
  int bh = nid >> 4;
  int bx = nid & 15;
  int bb = bh >> 4;
  int h = bh & 15;
  int q0A = (31 - bx) * 64;                           // long tile
  int q0B = bx * 64;                                  // mirror short tile
  int q0w = ((wv < 4) ? q0A : q0B) + (wv & 3) * 16;

  const unsigned short* kb = k + (size_t)bh * NN * 64;
  const unsigned short* vb = vT + (size_t)bh * 64 * NN;

  // Q fragments: raw GEMM output + in-register RoPE (pairs are adjacent).
  s16x8 qf[2];
  {
    int qrow = q0w + lo;
    const unsigned short* qp = qkvt + (size_t)(bb * NN + qrow) * QKVN + h * 64;
    const float2* tb = tab + (size_t)(bb * NN + qrow) * 32;
    #pragma unroll
    for (int ks = 0; ks < 2; ++ks) {
      s16x8 raw = *(const s16x8*)&qp[ks * 32 + hi * 8];
      #pragma unroll
      for (int e2 = 0; e2 < 4; ++e2) {
        float2 cs = tb[ks * 16 + hi * 4 + e2];
        float t1 = bf2f((unsigned short)raw[2 * e2]);
        float t2 = bf2f((unsigned short)raw[2 * e2 + 1]);
        float o1 = (t1 * cs.x - t2 * cs.y) * 0.18033688011112042f; // 0.125*log2e
        float o2 = (t1 * cs.y + t2 * cs.x) * 0.18033688011112042f;
        qf[ks][2 * e2]     = (short)f2bf(o1);
        qf[ks][2 * e2 + 1] = (short)f2bf(o2);
      }
    }
  }

  int off_[MMOD], end_[MMOD];
  #pragma unroll
  for (int m = 0; m < MMOD; ++m) {
    off_[m] = mods[(bb * MMOD + m) * 3 + 1];
    end_[m] = off_[m] + mods[(bb * MMOD + m) * 3 + 2];
  }
  int limit_l;
  {
    int r = q0w + lo;
    int L = r + 1;
    #pragma unroll
    for (int m = 0; m < MMOD; ++m)
      if (off_[m] <= r && end_[m] > L) L = end_[m];
    limit_l = L;
  }
  int minlim, kvmax_w;
  {
    int L = q0w + 1;
    #pragma unroll
    for (int m = 0; m < MMOD; ++m)
      if (off_[m] <= q0w && end_[m] > L) L = end_[m];
    minlim = L;
    int r = q0w + 15;
    int L2 = r + 1;
    #pragma unroll
    for (int m = 0; m < MMOD; ++m)
      if (off_[m] <= r && end_[m] > L2) L2 = end_[m];
    kvmax_w = L2;
  }
  int nt;
  {
    int ra = q0A + 63;
    int LA = ra + 1;
    #pragma unroll
    for (int m = 0; m < MMOD; ++m)
      if (off_[m] <= ra && end_[m] > LA) LA = end_[m];
    int rb2 = q0B + 63;
    int LB = rb2 + 1;
    #pragma unroll
    for (int m = 0; m < MMOD; ++m)
      if (off_[m] <= rb2 && end_[m] > LB) LB = end_[m];
    int Lblk = (LA > LB) ? LA : LB;
    nt = (Lblk + 127) >> 7;
  }

  // Stage 128-key K/V tile: 2 shots x 512 threads x 16B for each of K,V.
  #define STAGE_KV(B, KV0) do { \
    _Pragma("unroll") \
    for (int i_ = 0; i_ < 2; ++i_) { \
      int rK_ = i_ * 64 + (tid >> 3); \
      int csK_ = (lane & 7) ^ ((tid >> 3) & 7); \
      const unsigned short* gK_ = kb + (size_t)((KV0) + rK_) * 64 + csK_ * 8; \
      ASYNC_LDS16(gK_, &Ks[B][(i_ * 512 + wv * 64) * 8]); \
      int dhV_ = i_ * 32 + wv * 4 + (lane >> 4); \
      int ccV_ = ((lane & 7) ^ (dhV_ & 7)) | (lane & 8); \
      const unsigned short* gV_ = vb + (size_t)dhV_ * NN + (KV0) + ccV_ * 8; \
      ASYNC_LDS16(gV_, &Vs[B][(i_ * 512 + wv * 64) * 8]); \
    } \
  } while (0)

  float lr = 0.f;
  f32x4 accO[4] = {};

  STAGE_KV(0, 0);
  __syncthreads();
  int buf = 0;
  for (int t = 0; t < nt; ++t) {
    if (t + 1 < nt) STAGE_KV(buf ^ 1, (t + 1) << 7);
    int kv0 = t << 7;
    if (kv0 < kvmax_w) {
      // S^T = K Q^T; sv[cb][j] = S[qrow=lo][key=kv0+cb*16+hi*4+j], cb 0..7
      f32x4 sv[8];
      __builtin_amdgcn_s_setprio(1);
      #pragma unroll
      for (int cb = 0; cb < 8; ++cb) {
        int krow = cb * 16 + lo;
        int c0 = (hi) ^ (krow & 7);
        int c1 = (4 + hi) ^ (krow & 7);
        s16x8 kf0 = *(const s16x8*)&Ks[buf][krow * 64 + c0 * 8];
        s16x8 kf1 = *(const s16x8*)&Ks[buf][krow * 64 + c1 * 8];
        f32x4 z = {};
        z = __builtin_amdgcn_mfma_f32_16x16x32_bf16(kf0, qf[0], z, 0, 0, 0);
        z = __builtin_amdgcn_mfma_f32_16x16x32_bf16(kf1, qf[1], z, 0, 0, 0);
        sv[cb] = z;
      }
      __builtin_amdgcn_s_setprio(0);

      // p = exp2(sv - sv^3*k2)  (== exp(s - s^3/7500), e^-50 shift cancels)
      unsigned int pk_[8][2];
      bool edge = (kv0 + 128 > minlim);
      int kb0 = kv0 + hi * 4;
      #pragma unroll
      for (int cb = 0; cb < 8; ++cb) {
        float p[4];
        #pragma unroll
        for (int j = 0; j < 4; ++j) {
          float s = sv[cb][j];
          float u = __builtin_fmaf(s * s, -6.40604e-5f, 1.0f);
          float pp = __builtin_amdgcn_exp2f(s * u);
          if (edge && (kb0 + cb * 16 + j) >= limit_l) pp = 0.f;
          p[j] = pp;
        }
        lr += (p[0] + p[1]) + (p[2] + p[3]);
        pk_[cb][0] = cvt_pk_bf16(p[0], p[1]);
        pk_[cb][1] = cvt_pk_bf16(p[2], p[3]);
      }

      // pa[ks'] covers keys of cb = ks'*2 .. ks'*2+1 groups (sigma order)
      union { unsigned int u[4]; s16x8 v; } pa[4];
      #pragma unroll
      for (int kk = 0; kk < 4; ++kk) {
        pa[kk].u[0] = pk_[2 * kk][0];
        pa[kk].u[1] = pk_[2 * kk][1];
        pa[kk].u[2] = pk_[2 * kk + 1][0];
        pa[kk].u[3] = pk_[2 * kk + 1][1];
      }

      // PV from swizzled LDS (row stride 128): conflict-free b128 reads
      __builtin_amdgcn_s_setprio(1);
      #pragma unroll
      for (int ks = 0; ks < 4; ++ks) {
        #pragma unroll
        for (int cbo = 0; cbo < 4; ++cbo) {
          int vrow = cbo * 16 + lo;
          int vc = (ks * 4 + hi) ^ (vrow & 7);
          s16x8 vf = *(const s16x8*)&Vs[buf][vrow * 128 + vc * 8];
          accO[cbo] = __builtin_amdgcn_mfma_f32_16x16x32_bf16(pa[ks].v, vf, accO[cbo], 0, 0, 0);
        }
      }
      __builtin_amdgcn_s_setprio(0);
    }
    __syncthreads();
    buf ^= 1;
  }

  // denominator: total for qrow=lo, redistribute to output rows hi*4+j
  lr += __shfl_xor(lr, 16);
  lr += __shfl_xor(lr, 32);
  float rl[4];
  #pragma unroll
  for (int j = 0; j < 4; ++j)
    rl[j] = __builtin_amdgcn_rcpf(__shfl(lr, hi * 4 + j));

  #pragma unroll
  for (int cb = 0; cb < 4; ++cb)
    #pragma unroll
    for (int j = 0; j < 4; ++j) {
      int r = q0w + hi * 4 + j;
      float val = accO[cb][j] * rl[j];
      o[((size_t)(bb * NN) + r) * (HH * DHD) + h * 64 + cb * 16 + lo] = f2bf(val);
    }
}

// ---------------------------------------------------------------------------
extern "C" void kernel_launch(void* const* d_in, const int* in_sizes, int n_in,
                              void* d_out, int out_size, void* d_ws, size_t ws_size,
                              hipStream_t stream) {
  (void)in_sizes; (void)n_in; (void)out_size; (void)ws_size;
  const float* x      = (const float*)d_in[0];
  const float* tokens = (const float*)d_in[1];
  const float* gamma  = (const float*)d_in[2];
  const float* w_qkv  = (const float*)d_in[3];
  const float* w_out  = (const float*)d_in[4];
  const int*   mods   = (const int*)d_in[5];

  char* ws = (char*)d_ws;
  unsigned short* xn    = (unsigned short*)(ws + 0);           //  8 MB
  unsigned short* wqkvT = (unsigned short*)(ws + 8388608);     //  6 MB
  unsigned short* woutT = (unsigned short*)(ws + 14680064);    //  2 MB
  unsigned short* qkvt  = (unsigned short*)(ws + 16777216);    // 24 MB
  unsigned short* kd    = (unsigned short*)(ws + 50331648);    //  8 MB
  unsigned short* vTd   = (unsigned short*)(ws + 58720256);    //  8 MB
  unsigned short* attno = (unsigned short*)(ws + 67108864);    //  8 MB
  int*            pos   = (int*)(ws + 75497472);               // 16 KB
  float2*         tab   = (float2*)(ws + 75513856);            //  1 MB

  k_prep<<<BNROWS, 256, 0, stream>>>(x, tokens, gamma, mods, xn);
  k_pos<<<BB, 64, 0, stream>>>(mods, pos);
  k_tab<<<(BB * NN * 32) / 256, 256, 0, stream>>>(pos, tab);
  k_tr2<<<4096, dim3(32, 8), 0, stream>>>(w_qkv, w_out, wqkvT, woutT);
  k_gemmq<<<dim3(QKVN / 192, BNROWS / 128), 256, 0, stream>>>(xn, wqkvT, qkvt, BNROWS, QKVN, DD);
  k_ropevtr<<<BNROWS + 1024, 256, 0, stream>>>(qkvt, tab, kd, vTd);
  k_attn<<<dim3(16, BB * HH), 512, 0, stream>>>(qkvt, tab, kd, vTd, mods, attno);
  k_gemm_n64<true><<<dim3(DD / 64, BNROWS / 128), 256, 0, stream>>>(attno, woutT, (void*)d_out, BNROWS, DD, HH * DHD);
}

// Round 20
// 119.874 us; speedup vs baseline: 1.2753x; 1.0479x over previous
//
#include <hip/hip_runtime.h>
#include <stdint.h>

#define HH 16
#define DHD 64
#define BB 2
#define NN 2048
#define DD 1024
#define MMOD 4
#define LMAX 256
#define BNROWS (BB*NN)      // 4096
#define QKVN (3*HH*DHD)     // 3072

typedef __attribute__((ext_vector_type(4))) float f32x4;
typedef __attribute__((ext_vector_type(8))) short s16x8;
typedef __attribute__((ext_vector_type(4))) short s16x4;

__device__ __forceinline__ float bf2f(unsigned short b) {
  return __uint_as_float(((unsigned int)b) << 16);
}
__device__ __forceinline__ unsigned short f2bf(float f) {
  unsigned int u = __float_as_uint(f);
  u += 0x7fffu + ((u >> 16) & 1u);
  return (unsigned short)(u >> 16);
}
__device__ __forceinline__ unsigned int cvt_pk_bf16(float a, float b) {
  unsigned int r;
  asm("v_cvt_pk_bf16_f32 %0, %1, %2" : "=v"(r) : "v"(a), "v"(b));
  return r;
}

#define ASYNC_LDS16(g, l) \
  __builtin_amdgcn_global_load_lds((const __attribute__((address_space(1))) void*)(g), \
                                   (__attribute__((address_space(3))) void*)(l), 16, 0, 0)

// ---------------------------------------------------------------------------
// K1: merged prep: blocks 0..4095 = modality splice + norm (xn),
// 4096..8191 = weight transposes, 8192..8703 = RoPE cos/sin table with
// closed-form pos (interval-union count, no cumsum pass needed).
// ---------------------------------------------------------------------------
__global__ __launch_bounds__(256) void k_pre(const float* __restrict__ x,
                                             const float* __restrict__ tokens,
                                             const float* __restrict__ gamma,
                                             const int* __restrict__ mods,
                                             const float* __restrict__ w_qkv,
                                             const float* __restrict__ w_out,
                                             unsigned short* __restrict__ xn,
                                             unsigned short* __restrict__ wqkvT,
                                             unsigned short* __restrict__ woutT,
                                             float2* __restrict__ tab) {
  __shared__ float tile[32][33];
  __shared__ float red[4];
  int bid = blockIdx.x;
  int t = threadIdx.x;

  if (bid < BNROWS) {
    // ---- modality splice + norm + gamma ----
    int bs = bid;
    int bb = bs / NN, s = bs % NN;
    int c = t * 4;
    const float4 xv = *(const float4*)(x + (size_t)bs * DD + c);
    float4 acc = {0.f, 0.f, 0.f, 0.f};
    bool any = false;
    #pragma unroll
    for (int m = 0; m < MMOD; ++m) {
      int off = mods[(bb * MMOD + m) * 3 + 1];
      int ln  = mods[(bb * MMOD + m) * 3 + 2];
      if (s >= off && s < off + ln) {
        any = true;
        int rel = s - off;
        if (rel > LMAX - 1) rel = LMAX - 1;
        if (rel < 0) rel = 0;
        const float4 tv = *(const float4*)(tokens + ((size_t)(bb * MMOD + m) * LMAX + rel) * DD + c);
        acc.x += tv.x; acc.y += tv.y; acc.z += tv.z; acc.w += tv.w;
      }
    }
    float4 v = any ? acc : xv;
    float ss = v.x*v.x + v.y*v.y + v.z*v.z + v.w*v.w;
    #pragma unroll
    for (int o = 32; o; o >>= 1) ss += __shfl_xor(ss, o);
    int wv = t >> 6;
    if ((t & 63) == 0) red[wv] = ss;
    __syncthreads();
    float tot = red[0] + red[1] + red[2] + red[3];
    float norm = sqrtf(tot);
    norm = fmaxf(norm, 1e-12f);
    float sc = 32.0f / norm;   // sqrt(1024) = 32
    const float4 g = *(const float4*)(gamma + c);
    unsigned long long pk =
        (unsigned long long)f2bf(v.x * sc * (g.x + 1.f)) |
        ((unsigned long long)f2bf(v.y * sc * (g.y + 1.f)) << 16) |
        ((unsigned long long)f2bf(v.z * sc * (g.z + 1.f)) << 32) |
        ((unsigned long long)f2bf(v.w * sc * (g.w + 1.f)) << 48);
    *(unsigned long long*)(xn + (size_t)bs * DD + c) = pk;
  } else if (bid < BNROWS + 4096) {
    // ---- weight transposes f32 [R][C] -> bf16 [C][R] ----
    int b2 = bid - BNROWS;
    const float* in;
    unsigned short* out;
    int R, C, bx, by;
    if (b2 < 3072) {
      in = w_qkv; out = wqkvT; R = DD; C = QKVN;
      bx = b2 % 96; by = b2 / 96;
    } else {
      int b3 = b2 - 3072;
      in = w_out; out = woutT; R = HH * DHD; C = DD;
      bx = b3 % 32; by = b3 / 32;
    }
    int tx = t & 31, ty = t >> 5;
    #pragma unroll
    for (int k = 0; k < 4; ++k) {
      int r = by * 32 + ty + k * 8, c = bx * 32 + tx;
      tile[ty + k * 8][tx] = in[(size_t)r * C + c];
    }
    __syncthreads();
    #pragma unroll
    for (int k = 0; k < 4; ++k) {
      int oc = bx * 32 + ty + k * 8;
      int orr = by * 32 + tx;
      out[(size_t)oc * R + orr] = f2bf(tile[tx][ty + k * 8]);
    }
  } else {
    // ---- RoPE table with closed-form pos ----
    int gid = (bid - BNROWS - 4096) * 256 + t;   // 0..131071
    int p = gid & 31;
    int bs = gid >> 5;
    int bb = bs / NN, s = bs % NN;
    // intervals [o_m, e_m) of rotation-skipped positions
    int ov[MMOD], ev[MMOD];
    #pragma unroll
    for (int m = 0; m < MMOD; ++m) {
      int off = mods[(bb * MMOD + m) * 3 + 1];
      int ln  = mods[(bb * MMOD + m) * 3 + 2];
      ov[m] = off + 1;
      ev[m] = off + ln;
    }
    // sort by ov (4-element network)
    #define CSWP(a, b) if (ov[a] > ov[b]) { int t1 = ov[a]; ov[a] = ov[b]; ov[b] = t1; \
                                            int t2 = ev[a]; ev[a] = ev[b]; ev[b] = t2; }
    CSWP(0, 1) CSWP(2, 3) CSWP(0, 2) CSWP(1, 3) CSWP(1, 2)
    #undef CSWP
    // merge + clamped count of union ∩ [0, s]
    int s1 = s + 1;
    int cnt = 0;
    int curo = ov[0], cure = ev[0];
    #pragma unroll
    for (int m = 1; m < MMOD; ++m) {
      if (ov[m] <= cure) {
        cure = (ev[m] > cure) ? ev[m] : cure;
      } else {
        int lo2 = (s1 < curo) ? s1 : curo;
        int hi2 = (s1 < cure) ? s1 : cure;
        if (hi2 > lo2) cnt += hi2 - lo2;
        curo = ov[m]; cure = ev[m];
      }
    }
    {
      int lo2 = (s1 < curo) ? s1 : curo;
      int hi2 = (s1 < cure) ? s1 : cure;
      if (hi2 > lo2) cnt += hi2 - lo2;
    }
    int pos = s - cnt;
    float inv = expf(-((float)p / 32.f) * 9.210340371976184f); // 1/10000^(2p/64)
    float ang = (float)pos * inv;
    float sn, cs;
    sincosf(ang, &sn, &cs);
    tab[gid] = make_float2(cs, sn);
  }
}

// ---------------------------------------------------------------------------
// K4: QKV GEMM, BM=128 BN=192 BK=64, 4 waves (2x2, wave tile 64x96),
// acc[4][6], 80 KB LDS -> 2 blocks/CU; grid 512 = exactly one resident
// round. dbuf + XOR swz + chunked XCD swizzle. bf16 out.
// ---------------------------------------------------------------------------
__global__ __launch_bounds__(256) void k_gemmq(const unsigned short* __restrict__ A,
                                               const unsigned short* __restrict__ Bt,
                                               unsigned short* __restrict__ C,
                                               int M, int Nn, int K) {
  __shared__ unsigned short As[2][128 * 64];
  __shared__ unsigned short Bs[2][192 * 64];
  int tid = threadIdx.x;
  int lane = tid & 63, wv = tid >> 6;
  int lo = lane & 15, hi = lane >> 4;
  int nb = gridDim.x * gridDim.y;              // 512
  int fid = blockIdx.y * gridDim.x + blockIdx.x;
  int cpx = nb >> 3;
  int nid = (fid & 7) * cpx + (fid >> 3);      // contiguous chunk per XCD
  int m0 = (nid / gridDim.x) * 128;
  int n0 = (nid % gridDim.x) * 192;
  int wr = wv >> 1, wc = wv & 1;
  f32x4 acc[4][6] = {};

  int srow = tid >> 3;
  int scs  = ((tid & 7) ^ ((tid >> 3) & 7)) * 8;
  #define STAGE_Q(BUF, KT) do { \
    _Pragma("unroll") \
    for (int is_ = 0; is_ < 4; ++is_) { \
      int r_ = is_ * 32 + srow; \
      const unsigned short* ga_ = A + (size_t)(m0 + r_) * K + (KT) + scs; \
      ASYNC_LDS16(ga_, &As[BUF][(is_ * 256 + tid) * 8]); \
    } \
    _Pragma("unroll") \
    for (int is_ = 0; is_ < 6; ++is_) { \
      int r_ = is_ * 32 + srow; \
      const unsigned short* gb_ = Bt + (size_t)(n0 + r_) * K + (KT) + scs; \
      ASYNC_LDS16(gb_, &Bs[BUF][(is_ * 256 + tid) * 8]); \
    } \
  } while (0)

  int nt = K >> 6;
  STAGE_Q(0, 0);
  __syncthreads();
  int buf = 0;
  for (int t = 0; t < nt; ++t) {
    if (t + 1 < nt) STAGE_Q(buf ^ 1, (t + 1) << 6);
    #pragma unroll
    for (int ks = 0; ks < 2; ++ks) {
      s16x8 af[4], bfr[6];
      #pragma unroll
      for (int m = 0; m < 4; ++m) {
        int row = wr * 64 + m * 16 + lo;
        int cc = ((ks * 4 + hi) ^ (lo & 7)) * 8;
        af[m] = *(const s16x8*)&As[buf][row * 64 + cc];
      }
      #pragma unroll
      for (int nn = 0; nn < 6; ++nn) {
        int row = wc * 96 + nn * 16 + lo;
        int cc = ((ks * 4 + hi) ^ (lo & 7)) * 8;
        bfr[nn] = *(const s16x8*)&Bs[buf][row * 64 + cc];
      }
      #pragma unroll
      for (int m = 0; m < 4; ++m)
        #pragma unroll
        for (int nn = 0; nn < 6; ++nn)
          acc[m][nn] = __builtin_amdgcn_mfma_f32_16x16x32_bf16(af[m], bfr[nn], acc[m][nn], 0, 0, 0);
    }
    __syncthreads();
    buf ^= 1;
  }
  #undef STAGE_Q

  #pragma unroll
  for (int m = 0; m < 4; ++m) {
    #pragma unroll
    for (int nn = 0; nn < 6; ++nn) {
      int r0 = m0 + wr * 64 + m * 16 + hi * 4;
      int cc = n0 + wc * 96 + nn * 16 + lo;
      #pragma unroll
      for (int j = 0; j < 4; ++j)
        C[(size_t)(r0 + j) * Nn + cc] = f2bf(acc[m][nn][j]);
    }
  }
}

// ---------------------------------------------------------------------------
// K7: out-proj GEMM, BM=128 BN=64 (grid 512), 4 waves stacked, acc[2][4].
// ---------------------------------------------------------------------------
template<bool F32OUT>
__global__ __launch_bounds__(256) void k_gemm_n64(const unsigned short* __restrict__ A,
                                                  const unsigned short* __restrict__ Bt,
                                                  void* __restrict__ Cp,
                                                  int M, int Nn, int K) {
  __shared__ unsigned short As[2][128 * 64];
  __shared__ unsigned short Bs[2][64 * 64];
  int tid = threadIdx.x;
  int lane = tid & 63, wv = tid >> 6;
  int lo = lane & 15, hi = lane >> 4;
  int nb = gridDim.x * gridDim.y;
  int fid = blockIdx.y * gridDim.x + blockIdx.x;
  int cpx = nb >> 3;
  int nid = (fid & 7) * cpx + (fid >> 3);
  int m0 = (nid / gridDim.x) * 128;
  int n0 = (nid % gridDim.x) * 64;
  f32x4 acc[2][4] = {};

  int srow = tid >> 3;
  int scs  = ((tid & 7) ^ ((tid >> 3) & 7)) * 8;
  #define STAGE_N(BUF, KT) do { \
    _Pragma("unroll") \
    for (int is_ = 0; is_ < 4; ++is_) { \
      int r_ = is_ * 32 + srow; \
      const unsigned short* ga_ = A + (size_t)(m0 + r_) * K + (KT) + scs; \
      ASYNC_LDS16(ga_, &As[BUF][(is_ * 256 + wv * 64) * 8]); \
    } \
    _Pragma("unroll") \
    for (int is_ = 0; is_ < 2; ++is_) { \
      int r_ = is_ * 32 + srow; \
      const unsigned short* gb_ = Bt + (size_t)(n0 + r_) * K + (KT) + scs; \
      ASYNC_LDS16(gb_, &Bs[BUF][(is_ * 256 + wv * 64) * 8]); \
    } \
  } while (0)

  int nt = K >> 6;
  STAGE_N(0, 0);
  __syncthreads();
  int buf = 0;
  for (int t = 0; t < nt; ++t) {
    if (t + 1 < nt) STAGE_N(buf ^ 1, (t + 1) << 6);
    #pragma unroll
    for (int ks = 0; ks < 2; ++ks) {
      s16x8 af[2], bfr[4];
      #pragma unroll
      for (int m = 0; m < 2; ++m) {
        int row = wv * 32 + m * 16 + lo;
        int cc = ((ks * 4 + hi) ^ (lo & 7)) * 8;
        af[m] = *(const s16x8*)&As[buf][row * 64 + cc];
      }
      #pragma unroll
      for (int nn = 0; nn < 4; ++nn) {
        int row = nn * 16 + lo;
        int cc = ((ks * 4 + hi) ^ (lo & 7)) * 8;
        bfr[nn] = *(const s16x8*)&Bs[buf][row * 64 + cc];
      }
      #pragma unroll
      for (int m = 0; m < 2; ++m)
        #pragma unroll
        for (int nn = 0; nn < 4; ++nn)
          acc[m][nn] = __builtin_amdgcn_mfma_f32_16x16x32_bf16(af[m], bfr[nn], acc[m][nn], 0, 0, 0);
    }
    __syncthreads();
    buf ^= 1;
  }
  #undef STAGE_N

  #pragma unroll
  for (int m = 0; m < 2; ++m)
    #pragma unroll
    for (int nn = 0; nn < 4; ++nn) {
      int r0 = m0 + wv * 32 + m * 16 + hi * 4;
      int cc = n0 + nn * 16 + lo;
      #pragma unroll
      for (int j = 0; j < 4; ++j) {
        float val = acc[m][nn][j];
        if (F32OUT) ((float*)Cp)[(size_t)(r0 + j) * Nn + cc] = val;
        else        ((unsigned short*)Cp)[(size_t)(r0 + j) * Nn + cc] = f2bf(val);
      }
    }
}

// ---------------------------------------------------------------------------
// K5: merged K-RoPE + V transpose.
// blocks 0..4095: RoPE K (qkvt cols 1024..2047 -> kd)
// blocks 4096..5119: V -> sigma-permuted vT
// sigma(k): bits [b5 b4 b3 b2 b1 b0] -> 32*b5 + 16*b3 + 8*b2 + 4*b4 + b1b0
// ---------------------------------------------------------------------------
__global__ __launch_bounds__(256) void k_ropevtr(const unsigned short* __restrict__ qkvt,
                                                 const float2* __restrict__ tab,
                                                 unsigned short* __restrict__ kd,
                                                 unsigned short* __restrict__ vT) {
  __shared__ unsigned short t[64][72];
  int bid = blockIdx.x;
  if (bid < BNROWS) {
    int bs = bid;
    int bb = bs / NN, s = bs % NN;
    int lane = threadIdx.x & 63, wv = threadIdx.x >> 6;
    #pragma unroll
    for (int g = 16 + wv; g < 32; g += 4) {
      int h = g & 15;
      float val = bf2f(qkvt[(size_t)bs * QKVN + g * 64 + lane]);
      float partner = __shfl_xor(val, 1);
      float2 cs = tab[(size_t)bs * 32 + (lane >> 1)];
      float out;
      if ((lane & 1) == 0) out = val * cs.x - partner * cs.y;    // t1*cos - t2*sin
      else                 out = partner * cs.y + val * cs.x;    // t1*sin + t2*cos
      kd[((size_t)(bb * HH + h) * NN + s) * 64 + lane] = f2bf(out);
    }
  } else {
    int idx = bid - BNROWS;
    int s0 = (idx & 31) * 64, bh = idx >> 5, bb = bh >> 4, h = bh & 15;
    int tid = threadIdx.x;
    int r = tid >> 2, c0 = (tid & 3) * 16;
    int cw = c0 ^ (((r >> 4) & 3) << 4);
    const unsigned short* src = qkvt + (size_t)(bb * NN + s0 + r) * QKVN + 2048 + h * 64 + c0;
    *(s16x8*)&t[r][cw]     = *(const s16x8*)src;
    *(s16x8*)&t[r][cw + 8] = *(const s16x8*)(src + 8);
    __syncthreads();
    int dh = tid >> 2, sc = (tid & 3) * 16;
    int col2 = dh ^ ((tid & 3) << 4);
    s16x8 o1, o2;
    #pragma unroll
    for (int i = 0; i < 8; ++i) {
      o1[i] = (short)t[sc + i][col2];
      o2[i] = (short)t[sc + 8 + i][col2];
    }
    unsigned short* dst = vT + ((size_t)bh * 64 + dh) * NN + s0;
    int pb = (sc & 32) + (((sc >> 4) & 1) << 2);
    s16x4 g0 = __builtin_shufflevector(o1, o1, 0, 1, 2, 3);
    s16x4 g1 = __builtin_shufflevector(o1, o1, 4, 5, 6, 7);
    s16x4 g2 = __builtin_shufflevector(o2, o2, 0, 1, 2, 3);
    s16x4 g3 = __builtin_shufflevector(o2, o2, 4, 5, 6, 7);
    *(s16x4*)&dst[pb]      = g0;
    *(s16x4*)&dst[pb + 8]  = g1;
    *(s16x4*)&dst[pb + 16] = g2;
    *(s16x4*)&dst[pb + 24] = g3;
  }
}

// ---------------------------------------------------------------------------
// K6: flash attention (R14 exact). KVBLK=128, 8 waves, paired long/short
// q-tiles (XCD-contiguous map), dbuf K/V staging, swapped QK^T, cvt_pk P,
// PV b128 from XOR-swizzled sigma-permuted vT, in-register Q-RoPE.
// ---------------------------------------------------------------------------
__global__ __launch_bounds__(512) void k_attn(const unsigned short* __restrict__ qkvt,
                                              const float2* __restrict__ tab,
                                              const unsigned short* __restrict__ k,
                                              const unsigned short* __restrict__ vT,
                                              const int* __restrict__ mods,
                                              unsigned short* __restrict__ o) {
  __shared__ unsigned short Ks[2][128 * 64];   // 128 keys x 64 dh
  __shared__ unsigned short Vs[2][64 * 128];   // 64 dh x 128 keys
  int tid = threadIdx.x;
  int lane = tid & 63, wv = tid >> 6;
  int lo = lane & 15, hi = lane >> 4;

  int fid = blockIdx.y * gridDim.x + blockIdx.x;      // 0..511
  int nid = (fid & 7) * 64 + (fid >> 3);              // XCD-contiguous (R12)
  int bh = nid >> 4;
  int bx = nid & 15;
  int bb = bh >> 4;
  int h = bh & 15;
  int q0A = (31 - bx) * 64;                           // long tile
  int q0B = bx * 64;                                  // mirror short tile
  int q0w = ((wv < 4) ? q0A : q0B) + (wv & 3) * 16;

  const unsigned short* kb = k + (size_t)bh * NN * 64;
  const unsigned short* vb = vT + (size_t)bh * 64 * NN;

  // Q fragments: raw GEMM output + in-register RoPE (pairs are adjacent).
  s16x8 qf[2];
  {
    int qrow = q0w + lo;
    const unsigned short* qp = qkvt + (size_t)(bb * NN + qrow) * QKVN + h * 64;
    const float2* tb = tab + (size_t)(bb * NN + qrow) * 32;
    #pragma unroll
    for (int ks = 0; ks < 2; ++ks) {
      s16x8 raw = *(const s16x8*)&qp[ks * 32 + hi * 8];
      #pragma unroll
      for (int e2 = 0; e2 < 4; ++e2) {
        float2 cs = tb[ks * 16 + hi * 4 + e2];
        float t1 = bf2f((unsigned short)raw[2 * e2]);
        float t2 = bf2f((unsigned short)raw[2 * e2 + 1]);
        float o1 = (t1 * cs.x - t2 * cs.y) * 0.18033688011112042f; // 0.125*log2e
        float o2 = (t1 * cs.y + t2 * cs.x) * 0.18033688011112042f;
        qf[ks][2 * e2]     = (short)f2bf(o1);
        qf[ks][2 * e2 + 1] = (short)f2bf(o2);
      }
    }
  }

  int off_[MMOD], end_[MMOD];
  #pragma unroll
  for (int m = 0; m < MMOD; ++m) {
    off_[m] = mods[(bb * MMOD + m) * 3 + 1];
    end_[m] = off_[m] + mods[(bb * MMOD + m) * 3 + 2];
  }
  int limit_l;
  {
    int r = q0w + lo;
    int L = r + 1;
    #pragma unroll
    for (int m = 0; m < MMOD; ++m)
      if (off_[m] <= r && end_[m] > L) L = end_[m];
    limit_l = L;
  }
  int minlim, kvmax_w;
  {
    int L = q0w + 1;
    #pragma unroll
    for (int m = 0; m < MMOD; ++m)
      if (off_[m] <= q0w && end_[m] > L) L = end_[m];
    minlim = L;
    int r = q0w + 15;
    int L2 = r + 1;
    #pragma unroll
    for (int m = 0; m < MMOD; ++m)
      if (off_[m] <= r && end_[m] > L2) L2 = end_[m];
    kvmax_w = L2;
  }
  int nt;
  {
    int ra = q0A + 63;
    int LA = ra + 1;
    #pragma unroll
    for (int m = 0; m < MMOD; ++m)
      if (off_[m] <= ra && end_[m] > LA) LA = end_[m];
    int rb2 = q0B + 63;
    int LB = rb2 + 1;
    #pragma unroll
    for (int m = 0; m < MMOD; ++m)
      if (off_[m] <= rb2 && end_[m] > LB) LB = end_[m];
    int Lblk = (LA > LB) ? LA : LB;
    nt = (Lblk + 127) >> 7;
  }

  // Stage 128-key K/V tile: 2 shots x 512 threads x 16B for each of K,V.
  #define STAGE_KV(B, KV0) do { \
    _Pragma("unroll") \
    for (int i_ = 0; i_ < 2; ++i_) { \
      int rK_ = i_ * 64 + (tid >> 3); \
      int csK_ = (lane & 7) ^ ((tid >> 3) & 7); \
      const unsigned short* gK_ = kb + (size_t)((KV0) + rK_) * 64 + csK_ * 8; \
      ASYNC_LDS16(gK_, &Ks[B][(i_ * 512 + wv * 64) * 8]); \
      int dhV_ = i_ * 32 + wv * 4 + (lane >> 4); \
      int ccV_ = ((lane & 7) ^ (dhV_ & 7)) | (lane & 8); \
      const unsigned short* gV_ = vb + (size_t)dhV_ * NN + (KV0) + ccV_ * 8; \
      ASYNC_LDS16(gV_, &Vs[B][(i_ * 512 + wv * 64) * 8]); \
    } \
  } while (0)

  float lr = 0.f;
  f32x4 accO[4] = {};

  STAGE_KV(0, 0);
  __syncthreads();
  int buf = 0;
  for (int t = 0; t < nt; ++t) {
    if (t + 1 < nt) STAGE_KV(buf ^ 1, (t + 1) << 7);
    int kv0 = t << 7;
    if (kv0 < kvmax_w) {
      // S^T = K Q^T; sv[cb][j] = S[qrow=lo][key=kv0+cb*16+hi*4+j], cb 0..7
      f32x4 sv[8];
      __builtin_amdgcn_s_setprio(1);
      #pragma unroll
      for (int cb = 0; cb < 8; ++cb) {
        int krow = cb * 16 + lo;
        int c0 = (hi) ^ (krow & 7);
        int c1 = (4 + hi) ^ (krow & 7);
        s16x8 kf0 = *(const s16x8*)&Ks[buf][krow * 64 + c0 * 8];
        s16x8 kf1 = *(const s16x8*)&Ks[buf][krow * 64 + c1 * 8];
        f32x4 z = {};
        z = __builtin_amdgcn_mfma_f32_16x16x32_bf16(kf0, qf[0], z, 0, 0, 0);
        z = __builtin_amdgcn_mfma_f32_16x16x32_bf16(kf1, qf[1], z, 0, 0, 0);
        sv[cb] = z;
      }
      __builtin_amdgcn_s_setprio(0);

      // p = exp2(sv - sv^3*k2)  (== exp(s - s^3/7500), e^-50 shift cancels)
      unsigned int pk_[8][2];
      bool edge = (kv0 + 128 > minlim);
      int kb0 = kv0 + hi * 4;
      #pragma unroll
      for (int cb = 0; cb < 8; ++cb) {
        float p[4];
        #pragma unroll
        for (int j = 0; j < 4; ++j) {
          float s = sv[cb][j];
          float u = __builtin_fmaf(s * s, -6.40604e-5f, 1.0f);
          float pp = __builtin_amdgcn_exp2f(s * u);
          if (edge && (kb0 + cb * 16 + j) >= limit_l) pp = 0.f;
          p[j] = pp;
        }
        lr += (p[0] + p[1]) + (p[2] + p[3]);
        pk_[cb][0] = cvt_pk_bf16(p[0], p[1]);
        pk_[cb][1] = cvt_pk_bf16(p[2], p[3]);
      }

      // pa[ks'] covers keys of cb = ks'*2 .. ks'*2+1 groups (sigma order)
      union { unsigned int u[4]; s16x8 v; } pa[4];
      #pragma unroll
      for (int kk = 0; kk < 4; ++kk) {
        pa[kk].u[0] = pk_[2 * kk][0];
        pa[kk].u[1] = pk_[2 * kk][1];
        pa[kk].u[2] = pk_[2 * kk + 1][0];
        pa[kk].u[3] = pk_[2 * kk + 1][1];
      }

      // PV from swizzled LDS (row stride 128): conflict-free b128 reads
      __builtin_amdgcn_s_setprio(1);
      #pragma unroll
      for (int ks = 0; ks < 4; ++ks) {
        #pragma unroll
        for (int cbo = 0; cbo < 4; ++cbo) {
          int vrow = cbo * 16 + lo;
          int vc = (ks * 4 + hi) ^ (vrow & 7);
          s16x8 vf = *(const s16x8*)&Vs[buf][vrow * 128 + vc * 8];
          accO[cbo] = __builtin_amdgcn_mfma_f32_16x16x32_bf16(pa[ks].v, vf, accO[cbo], 0, 0, 0);
        }
      }
      __builtin_amdgcn_s_setprio(0);
    }
    __syncthreads();
    buf ^= 1;
  }

  // denominator: total for qrow=lo, redistribute to output rows hi*4+j
  lr += __shfl_xor(lr, 16);
  lr += __shfl_xor(lr, 32);
  float rl[4];
  #pragma unroll
  for (int j = 0; j < 4; ++j)
    rl[j] = __builtin_amdgcn_rcpf(__shfl(lr, hi * 4 + j));

  #pragma unroll
  for (int cb = 0; cb < 4; ++cb)
    #pragma unroll
    for (int j = 0; j < 4; ++j) {
      int r = q0w + hi * 4 + j;
      float val = accO[cb][j] * rl[j];
      o[((size_t)(bb * NN) + r) * (HH * DHD) + h * 64 + cb * 16 + lo] = f2bf(val);
    }
}

// ---------------------------------------------------------------------------
extern "C" void kernel_launch(void* const* d_in, const int* in_sizes, int n_in,
                              void* d_out, int out_size, void* d_ws, size_t ws_size,
                              hipStream_t stream) {
  (void)in_sizes; (void)n_in; (void)out_size; (void)ws_size;
  const float* x      = (const float*)d_in[0];
  const float* tokens = (const float*)d_in[1];
  const float* gamma  = (const float*)d_in[2];
  const float* w_qkv  = (const float*)d_in[3];
  const float* w_out  = (const float*)d_in[4];
  const int*   mods   = (const int*)d_in[5];

  char* ws = (char*)d_ws;
  unsigned short* xn    = (unsigned short*)(ws + 0);           //  8 MB
  unsigned short* wqkvT = (unsigned short*)(ws + 8388608);     //  6 MB
  unsigned short* woutT = (unsigned short*)(ws + 14680064);    //  2 MB
  unsigned short* qkvt  = (unsigned short*)(ws + 16777216);    // 24 MB
  unsigned short* kd    = (unsigned short*)(ws + 50331648);    //  8 MB
  unsigned short* vTd   = (unsigned short*)(ws + 58720256);    //  8 MB
  unsigned short* attno = (unsigned short*)(ws + 67108864);    //  8 MB
  float2*         tab   = (float2*)(ws + 75513856);            //  1 MB

  k_pre<<<BNROWS + 4096 + 512, 256, 0, stream>>>(x, tokens, gamma, mods, w_qkv, w_out,
                                                 xn, wqkvT, woutT, tab);
  k_gemmq<<<dim3(QKVN / 192, BNROWS / 128), 256, 0, stream>>>(xn, wqkvT, qkvt, BNROWS, QKVN, DD);
  k_ropevtr<<<BNROWS + 1024, 256, 0, stream>>>(qkvt, tab, kd, vTd);
  k_attn<<<dim3(16, BB * HH), 512, 0, stream>>>(qkvt, tab, kd, vTd, mods, attno);
  k_gemm_n64<true><<<dim3(DD / 64, BNROWS / 128), 256, 0, stream>>>(attno, woutT, (void*)d_out, BNROWS, DD, HH * DHD);
}